// Round 1
// baseline (5494.844 us; speedup 1.0000x reference)
//
#include <hip/hip_runtime.h>

// Problem constants (asserted by construction: N_A=N_B=30000, V=2, D=128)
#define V 2
#define D 128
#define NODE_ROW (V * D)   // 256 floats per node across views
#define PR 16              // rows per block in k_proj
#define AP 8               // (n,v) pairs per block in k_attn
#define AR (AP * 2)        // x-rows per block in k_attn (P=2)

__device__ __forceinline__ float wave_reduce_sum(float v) {
    #pragma unroll
    for (int o = 32; o > 0; o >>= 1) v += __shfl_down(v, o, 64);
    return v;
}

// out[dst[e]] += feat[src[e]] * val[e]   over [V*D]=256-float node rows.
// One wave per edge; lane handles one float4 (64*16B = 1KB row).
__global__ __launch_bounds__(256) void k_spmm(
    const float* __restrict__ feat, const int* __restrict__ src,
    const int* __restrict__ dst, const float* __restrict__ val,
    float* __restrict__ out, int E) {
    int e = blockIdx.x * 4 + (threadIdx.x >> 6);
    if (e >= E) return;
    int lane = threadIdx.x & 63;
    int s = src[e], d = dst[e];
    float w = val[e];
    float4 f = ((const float4*)(feat + (size_t)s * NODE_ROW))[lane];
    float* op = out + (size_t)d * NODE_ROW + lane * 4;
    atomicAdd(op + 0, f.x * w);
    atomicAdd(op + 1, f.y * w);
    atomicAdd(op + 2, f.z * w);
    atomicAdd(op + 3, f.w * w);
}

// in-place l2norm over last dim (128) ; one wave per row
__global__ __launch_bounds__(256) void k_l2norm(float* __restrict__ buf, int rows) {
    int r = blockIdx.x * 4 + (threadIdx.x >> 6);
    if (r >= rows) return;
    int lane = threadIdx.x & 63;
    float2* p = (float2*)(buf + (size_t)r * D) + lane;
    float2 x = *p;
    float ss = x.x * x.x + x.y * x.y;
    ss = wave_reduce_sum(ss);
    ss = __shfl(ss, 0, 64);
    float scale = 1.0f / fmaxf(sqrtf(ss), 1e-12f);
    x.x *= scale; x.y *= scale;
    *p = x;
}

// Fused: l2norm(in row) -> y = xn @ W^T + b -> LayerNorm(g,be) -> ReLU
// writes into xbuf at metapath slot p:  xbuf[(row*2+p)*128 + j]
// block = 128 threads (thread j owns output column j), PR rows per block.
__global__ __launch_bounds__(128) void k_proj(
    const float* __restrict__ in, const float* __restrict__ W,
    const float* __restrict__ b, const float* __restrict__ g,
    const float* __restrict__ be, float* __restrict__ xbuf, int p) {
    __shared__ float xin[PR][D];
    __shared__ float yb[PR][D];
    __shared__ float scale[PR];
    __shared__ float mu_s[PR], rs_s[PR];
    int t = threadIdx.x;
    size_t rowbase = (size_t)blockIdx.x * PR;

    // load PR rows (PR*128 floats)
    const float4* gin = (const float4*)(in + rowbase * D);
    float4* sxin = (float4*)&xin[0][0];
    for (int i = t; i < PR * D / 4; i += 128) sxin[i] = gin[i];
    __syncthreads();

    // l2 scale per row: 8 threads per row
    {
        int r = t >> 3, i = t & 7;
        float ss = 0.f;
        const float* xr = xin[r] + i * 16;
        #pragma unroll
        for (int c = 0; c < 16; c++) { float v = xr[c]; ss += v * v; }
        ss += __shfl_down(ss, 4, 8);
        ss += __shfl_down(ss, 2, 8);
        ss += __shfl_down(ss, 1, 8);
        if (i == 0) scale[r] = 1.0f / fmaxf(sqrtf(ss), 1e-12f);
    }
    __syncthreads();

    int j = t;
    float acc[PR];
    #pragma unroll
    for (int r = 0; r < PR; r++) acc[r] = 0.f;
    const float4* wrow = (const float4*)(W + (size_t)j * D);
    #pragma unroll
    for (int kc = 0; kc < 4; kc++) {
        float4 w[8];
        #pragma unroll
        for (int q = 0; q < 8; q++) w[q] = wrow[kc * 8 + q];
        #pragma unroll
        for (int r = 0; r < PR; r++) {
            const float4* xr = (const float4*)&xin[r][kc * 32];
            float a = acc[r];
            #pragma unroll
            for (int q = 0; q < 8; q++) {
                float4 xv = xr[q];
                a += xv.x * w[q].x + xv.y * w[q].y + xv.z * w[q].z + xv.w * w[q].w;
            }
            acc[r] = a;
        }
    }
    float bj = b[j];
    #pragma unroll
    for (int r = 0; r < PR; r++) yb[r][j] = bj + scale[r] * acc[r];
    __syncthreads();

    // LayerNorm stats per row
    {
        int r = t >> 3, i = t & 7;
        float s1 = 0.f, s2 = 0.f;
        const float* yr = yb[r] + i * 16;
        #pragma unroll
        for (int c = 0; c < 16; c++) { float v = yr[c]; s1 += v; s2 += v * v; }
        s1 += __shfl_down(s1, 4, 8); s2 += __shfl_down(s2, 4, 8);
        s1 += __shfl_down(s1, 2, 8); s2 += __shfl_down(s2, 2, 8);
        s1 += __shfl_down(s1, 1, 8); s2 += __shfl_down(s2, 1, 8);
        if (i == 0) {
            float mu = s1 / D;
            float var = s2 / D - mu * mu;
            mu_s[r] = mu;
            rs_s[r] = rsqrtf(var + 1e-5f);
        }
    }
    __syncthreads();

    float gj = g[j], bej = be[j];
    #pragma unroll
    for (int r = 0; r < PR; r++) {
        float v = (yb[r][j] - mu_s[r]) * rs_s[r] * gj + bej;
        v = fmaxf(v, 0.f);
        xbuf[((rowbase + r) * 2 + p) * D + j] = v;
    }
}

// Fused MHA over P=2 + residual + LN + mean over P.
// block = 384 threads, AP (n,v) pairs (= AR x-rows) per block.
__global__ __launch_bounds__(384) void k_attn(
    const float* __restrict__ xbuf,
    const float* __restrict__ Win, const float* __restrict__ binq,
    const float* __restrict__ Wout, const float* __restrict__ bout,
    const float* __restrict__ lng, const float* __restrict__ lnb,
    float* __restrict__ out) {
    __shared__ float xs[AR][D];        // x rows (residual)            8KB
    __shared__ float qkv[AR][3 * D];   // qkv; cols 0..127 reused as y 24KB
    __shared__ float os[AR][D];        // attention output o           8KB
    __shared__ float aw[AP][4][2][2];  // softmax weights
    __shared__ float mu_s[AR], rs_s[AR];
    int t = threadIdx.x;
    size_t pairbase = (size_t)blockIdx.x * AP;
    size_t rowbase = pairbase * 2;

    const float4* gx = (const float4*)(xbuf + rowbase * D);
    float4* sx = (float4*)&xs[0][0];
    for (int i = t; i < AR * D / 4; i += 384) sx[i] = gx[i];
    __syncthreads();

    // QKV: thread j in 0..383 computes column j for all AR rows
    {
        int j = t;
        float acc[AR];
        #pragma unroll
        for (int r = 0; r < AR; r++) acc[r] = 0.f;
        const float4* wrow = (const float4*)(Win + (size_t)j * D);
        #pragma unroll
        for (int kc = 0; kc < 4; kc++) {
            float4 w[8];
            #pragma unroll
            for (int q = 0; q < 8; q++) w[q] = wrow[kc * 8 + q];
            #pragma unroll
            for (int r = 0; r < AR; r++) {
                const float4* xr = (const float4*)&xs[r][kc * 32];
                float a = acc[r];
                #pragma unroll
                for (int q = 0; q < 8; q++) {
                    float4 xv = xr[q];
                    a += xv.x * w[q].x + xv.y * w[q].y + xv.z * w[q].z + xv.w * w[q].w;
                }
                acc[r] = a;
            }
        }
        float bj = binq[j];
        float sc = (j < D) ? 0.17677669529663687f : 1.0f; // q * dh^-0.5
        #pragma unroll
        for (int r = 0; r < AR; r++) qkv[r][j] = (acc[r] + bj) * sc;
    }
    __syncthreads();

    // scores (2x2 per head) + softmax; 32 threads = AP pairs x 4 heads
    if (t < AP * 4) {
        int pp = t >> 2, h = t & 3;
        int r0 = pp * 2, r1 = r0 + 1;
        const float* q0 = &qkv[r0][h * 32];
        const float* q1 = &qkv[r1][h * 32];
        const float* k0 = &qkv[r0][D + h * 32];
        const float* k1 = &qkv[r1][D + h * 32];
        float s00 = 0, s01 = 0, s10 = 0, s11 = 0;
        #pragma unroll
        for (int e = 0; e < 32; e++) {
            float a0 = q0[e], a1 = q1[e], c0 = k0[e], c1 = k1[e];
            s00 += a0 * c0; s01 += a0 * c1; s10 += a1 * c0; s11 += a1 * c1;
        }
        float m0 = fmaxf(s00, s01);
        float e00 = __expf(s00 - m0), e01 = __expf(s01 - m0);
        float i0 = 1.f / (e00 + e01);
        aw[pp][h][0][0] = e00 * i0; aw[pp][h][0][1] = e01 * i0;
        float m1 = fmaxf(s10, s11);
        float e10 = __expf(s10 - m1), e11 = __expf(s11 - m1);
        float i1 = 1.f / (e10 + e11);
        aw[pp][h][1][0] = e10 * i1; aw[pp][h][1][1] = e11 * i1;
    }
    __syncthreads();

    // o = a @ v : AR*128 outputs
    for (int idx = t; idx < AR * D; idx += 384) {
        int r = idx >> 7;
        int j = idx & 127;
        int pp = r >> 1, pq = r & 1, h = j >> 5;
        float a0 = aw[pp][h][pq][0], a1 = aw[pp][h][pq][1];
        os[r][j] = a0 * qkv[pp * 2][2 * D + j] + a1 * qkv[pp * 2 + 1][2 * D + j];
    }
    __syncthreads();

    // out-proj + bias + residual; thread j<128 owns column j; y into qkv[r][j]
    if (t < D) {
        int j = t;
        float acc[AR];
        #pragma unroll
        for (int r = 0; r < AR; r++) acc[r] = 0.f;
        const float4* wrow = (const float4*)(Wout + (size_t)j * D);
        #pragma unroll
        for (int kc = 0; kc < 4; kc++) {
            float4 w[8];
            #pragma unroll
            for (int q = 0; q < 8; q++) w[q] = wrow[kc * 8 + q];
            #pragma unroll
            for (int r = 0; r < AR; r++) {
                const float4* orr = (const float4*)&os[r][kc * 32];
                float a = acc[r];
                #pragma unroll
                for (int q = 0; q < 8; q++) {
                    float4 xv = orr[q];
                    a += xv.x * w[q].x + xv.y * w[q].y + xv.z * w[q].z + xv.w * w[q].w;
                }
                acc[r] = a;
            }
        }
        float bj = bout[j];
        #pragma unroll
        for (int r = 0; r < AR; r++) qkv[r][j] = acc[r] + bj + xs[r][j];
    }
    __syncthreads();

    // LN stats per row (8 threads/row over 128 cols)
    if (t < 128) {
        int r = t >> 3, i = t & 7;
        float s1 = 0.f, s2 = 0.f;
        const float* yr = &qkv[r][i * 16];
        #pragma unroll
        for (int c = 0; c < 16; c++) { float v = yr[c]; s1 += v; s2 += v * v; }
        s1 += __shfl_down(s1, 4, 8); s2 += __shfl_down(s2, 4, 8);
        s1 += __shfl_down(s1, 2, 8); s2 += __shfl_down(s2, 2, 8);
        s1 += __shfl_down(s1, 1, 8); s2 += __shfl_down(s2, 1, 8);
        if (i == 0) {
            float mu = s1 / D;
            float var = s2 / D - mu * mu;
            mu_s[r] = mu; rs_s[r] = rsqrtf(var + 1e-5f);
        }
    }
    __syncthreads();

    // LN apply + mean over P, write final output
    if (t < 128) {
        int j = t;
        float gj = lng[j], bj = lnb[j];
        #pragma unroll
        for (int pp = 0; pp < AP; pp++) {
            int r0 = pp * 2, r1 = r0 + 1;
            float v0 = (qkv[r0][j] - mu_s[r0]) * rs_s[r0] * gj + bj;
            float v1 = (qkv[r1][j] - mu_s[r1]) * rs_s[r1] * gj + bj;
            out[(pairbase + pp) * D + j] = 0.5f * (v0 + v1);
        }
    }
}

extern "C" void kernel_launch(void* const* d_in, const int* in_sizes, int n_in,
                              void* d_out, int out_size, void* d_ws, size_t ws_size,
                              hipStream_t stream) {
    const float* feat_A = (const float*)d_in[0];
    const float* feat_B = (const float*)d_in[1];
    const int*   src_ab = (const int*)d_in[2];
    const int*   dst_ab = (const int*)d_in[3];
    const float* val_ab = (const float*)d_in[4];
    const int*   src_ba = (const int*)d_in[5];
    const int*   dst_ba = (const int*)d_in[6];
    const float* val_ba = (const float*)d_in[7];
    const float* W1 = (const float*)d_in[8];
    const float* b1 = (const float*)d_in[9];
    const float* g1 = (const float*)d_in[10];
    const float* be1 = (const float*)d_in[11];
    const float* W2 = (const float*)d_in[12];
    const float* b2 = (const float*)d_in[13];
    const float* g2 = (const float*)d_in[14];
    const float* be2 = (const float*)d_in[15];
    const float* Win = (const float*)d_in[16];
    const float* binq = (const float*)d_in[17];
    const float* Wout = (const float*)d_in[18];
    const float* bout = (const float*)d_in[19];
    const float* lng = (const float*)d_in[20];
    const float* lnb = (const float*)d_in[21];

    int E = in_sizes[2];
    int rowsA = in_sizes[0] / D;   // N_A*V = 60000 (divisible by PR and AP)
    int rowsB = in_sizes[1] / D;   // N_B*V = 60000

    float* bufB  = (float*)d_ws;                      // [rowsB, 128]
    float* bufA1 = bufB  + (size_t)rowsB * D;         // [rowsA, 128]
    float* bufA2 = bufA1 + (size_t)rowsA * D;         // [rowsA, 128]
    float* xbuf  = bufA2 + (size_t)rowsA * D;         // [rowsA*2, 128]

    // zero accumulation buffers (ws is poisoned each call)
    hipMemsetAsync(bufB, 0, ((size_t)rowsB + 2 * (size_t)rowsA) * D * sizeof(float), stream);

    int eb = (E + 3) / 4;
    // metapath A->B->A
    k_spmm<<<eb, 256, 0, stream>>>(feat_A, src_ab, dst_ab, val_ab, bufB, E);
    k_l2norm<<<(rowsB + 3) / 4, 256, 0, stream>>>(bufB, rowsB);
    k_spmm<<<eb, 256, 0, stream>>>(bufB, src_ba, dst_ba, val_ba, bufA1, E);
    k_proj<<<rowsA / PR, 128, 0, stream>>>(bufA1, W1, b1, g1, be1, xbuf, 0);
    // metapath B->A
    k_spmm<<<eb, 256, 0, stream>>>(feat_B, src_ba, dst_ba, val_ba, bufA2, E);
    k_proj<<<rowsA / PR, 128, 0, stream>>>(bufA2, W2, b2, g2, be2, xbuf, 1);
    // MHA + residual + LN + mean
    k_attn<<<rowsA / AP, 384, 0, stream>>>(xbuf, Win, binq, Wout, bout, lng, lnb,
                                           (float*)d_out);
}

// Round 2
// 1028.467 us; speedup vs baseline: 5.3428x; 5.3428x over previous
//
#include <hip/hip_runtime.h>

// Problem constants: N_A=N_B=30000, V=2, D=128
#define D 128
#define NODE_ROW 256       // V*D floats per node
#define PR 16              // rows per block in k_proj
#define AP 8               // (n,v) pairs per block in k_attn
#define AR (AP * 2)        // x-rows per block in k_attn (P=2)

// ---------------- CSR build ----------------

__global__ __launch_bounds__(256) void k_hist(
    const int* __restrict__ dst_ab, const int* __restrict__ dst_ba,
    int* __restrict__ cnt_ab, int* __restrict__ cnt_ba, int E) {
    int i = blockIdx.x * 256 + threadIdx.x;
    if (i >= E) return;
    atomicAdd(&cnt_ab[dst_ab[i]], 1);
    atomicAdd(&cnt_ba[dst_ba[i]], 1);
}

// single-block exclusive scan of cnt[0..n) -> start[0..n], start[n]=total
__global__ __launch_bounds__(1024) void k_scan(
    const int* __restrict__ cnt, int* __restrict__ start, int n) {
    __shared__ int part[1024];
    int t = threadIdx.x;
    int chunk = (n + 1023) >> 10;
    int lo = min(t * chunk, n), hi = min(lo + chunk, n);
    int s = 0;
    for (int i = lo; i < hi; i++) s += cnt[i];
    part[t] = s;
    __syncthreads();
    for (int d = 1; d < 1024; d <<= 1) {
        int v = (t >= d) ? part[t - d] : 0;
        __syncthreads();
        part[t] += v;
        __syncthreads();
    }
    int off = part[t] - s;  // exclusive prefix
    for (int i = lo; i < hi; i++) { start[i] = off; off += cnt[i]; }
    if (t == 1023) start[n] = off;
}

__global__ __launch_bounds__(256) void k_scatter(
    const int* __restrict__ src_ab, const int* __restrict__ dst_ab,
    const float* __restrict__ val_ab,
    const int* __restrict__ src_ba, const int* __restrict__ dst_ba,
    const float* __restrict__ val_ba,
    const int* __restrict__ start_ab, const int* __restrict__ start_ba,
    int* __restrict__ cnt_ab, int* __restrict__ cnt_ba,
    int2* __restrict__ ep_ab, int2* __restrict__ ep_ba, int E) {
    int i = blockIdx.x * 256 + threadIdx.x;
    if (i >= E) return;
    {
        int dd = dst_ab[i];
        int pos = start_ab[dd] + atomicAdd(&cnt_ab[dd], 1);
        ep_ab[pos] = make_int2(src_ab[i], __float_as_int(val_ab[i]));
    }
    {
        int dd = dst_ba[i];
        int pos = start_ba[dd] + atomicAdd(&cnt_ba[dd], 1);
        ep_ba[pos] = make_int2(src_ba[i], __float_as_int(val_ba[i]));
    }
}

// ---------------- gather SpMM ----------------

// out[node] = l2norm_per_view( sum_e val[e]*feat[src[e]] ), one wave per node
__global__ __launch_bounds__(256) void k_gather_norm(
    const float* __restrict__ feat, const int2* __restrict__ ep,
    const int* __restrict__ start, float* __restrict__ out, int n) {
    int node = blockIdx.x * 4 + (threadIdx.x >> 6);
    if (node >= n) return;
    int lane = threadIdx.x & 63;
    int lo = start[node], hi = start[node + 1];
    float4 acc = make_float4(0.f, 0.f, 0.f, 0.f);
    int i = lo;
    for (; i + 1 < hi; i += 2) {
        int2 p0 = ep[i], p1 = ep[i + 1];
        float w0 = __int_as_float(p0.y), w1 = __int_as_float(p1.y);
        float4 f0 = ((const float4*)(feat + (size_t)p0.x * NODE_ROW))[lane];
        float4 f1 = ((const float4*)(feat + (size_t)p1.x * NODE_ROW))[lane];
        acc.x += w0 * f0.x + w1 * f1.x;
        acc.y += w0 * f0.y + w1 * f1.y;
        acc.z += w0 * f0.z + w1 * f1.z;
        acc.w += w0 * f0.w + w1 * f1.w;
    }
    if (i < hi) {
        int2 p0 = ep[i];
        float w0 = __int_as_float(p0.y);
        float4 f0 = ((const float4*)(feat + (size_t)p0.x * NODE_ROW))[lane];
        acc.x += w0 * f0.x; acc.y += w0 * f0.y;
        acc.z += w0 * f0.z; acc.w += w0 * f0.w;
    }
    // l2norm per view: lanes 0..31 = view0, 32..63 = view1
    float ss = acc.x * acc.x + acc.y * acc.y + acc.z * acc.z + acc.w * acc.w;
    #pragma unroll
    for (int o = 16; o > 0; o >>= 1) ss += __shfl_xor(ss, o, 32);
    float sc = 1.0f / fmaxf(sqrtf(ss), 1e-12f);
    acc.x *= sc; acc.y *= sc; acc.z *= sc; acc.w *= sc;
    ((float4*)(out + (size_t)node * NODE_ROW))[lane] = acc;
}

// fused: outP[node] = sum val*featP[src] ; outQ[node] = sum val*featQ[src]
// (no norm — consumer k_proj l2norms). One wave per node.
__global__ __launch_bounds__(256) void k_gather2(
    const float* __restrict__ featP, const float* __restrict__ featQ,
    const int2* __restrict__ ep, const int* __restrict__ start,
    float* __restrict__ outP, float* __restrict__ outQ, int n) {
    int node = blockIdx.x * 4 + (threadIdx.x >> 6);
    if (node >= n) return;
    int lane = threadIdx.x & 63;
    int lo = start[node], hi = start[node + 1];
    float4 aP = make_float4(0.f, 0.f, 0.f, 0.f);
    float4 aQ = make_float4(0.f, 0.f, 0.f, 0.f);
    for (int i = lo; i < hi; i++) {
        int2 p = ep[i];
        float w = __int_as_float(p.y);
        size_t off = (size_t)p.x * NODE_ROW;
        float4 fP = ((const float4*)(featP + off))[lane];
        float4 fQ = ((const float4*)(featQ + off))[lane];
        aP.x += w * fP.x; aP.y += w * fP.y; aP.z += w * fP.z; aP.w += w * fP.w;
        aQ.x += w * fQ.x; aQ.y += w * fQ.y; aQ.z += w * fQ.z; aQ.w += w * fQ.w;
    }
    ((float4*)(outP + (size_t)node * NODE_ROW))[lane] = aP;
    ((float4*)(outQ + (size_t)node * NODE_ROW))[lane] = aQ;
}

// ---------------- dense epilogue (unchanged from R1) ----------------

// Fused: l2norm(in row) -> y = xn @ W^T + b -> LayerNorm(g,be) -> ReLU
__global__ __launch_bounds__(128) void k_proj(
    const float* __restrict__ in, const float* __restrict__ W,
    const float* __restrict__ b, const float* __restrict__ g,
    const float* __restrict__ be, float* __restrict__ xbuf, int p) {
    __shared__ float xin[PR][D];
    __shared__ float yb[PR][D];
    __shared__ float scale[PR];
    __shared__ float mu_s[PR], rs_s[PR];
    int t = threadIdx.x;
    size_t rowbase = (size_t)blockIdx.x * PR;

    const float4* gin = (const float4*)(in + rowbase * D);
    float4* sxin = (float4*)&xin[0][0];
    for (int i = t; i < PR * D / 4; i += 128) sxin[i] = gin[i];
    __syncthreads();

    {
        int r = t >> 3, i = t & 7;
        float ss = 0.f;
        const float* xr = xin[r] + i * 16;
        #pragma unroll
        for (int c = 0; c < 16; c++) { float v = xr[c]; ss += v * v; }
        ss += __shfl_down(ss, 4, 8);
        ss += __shfl_down(ss, 2, 8);
        ss += __shfl_down(ss, 1, 8);
        if (i == 0) scale[r] = 1.0f / fmaxf(sqrtf(ss), 1e-12f);
    }
    __syncthreads();

    int j = t;
    float acc[PR];
    #pragma unroll
    for (int r = 0; r < PR; r++) acc[r] = 0.f;
    const float4* wrow = (const float4*)(W + (size_t)j * D);
    #pragma unroll
    for (int kc = 0; kc < 4; kc++) {
        float4 w[8];
        #pragma unroll
        for (int q = 0; q < 8; q++) w[q] = wrow[kc * 8 + q];
        #pragma unroll
        for (int r = 0; r < PR; r++) {
            const float4* xr = (const float4*)&xin[r][kc * 32];
            float a = acc[r];
            #pragma unroll
            for (int q = 0; q < 8; q++) {
                float4 xv = xr[q];
                a += xv.x * w[q].x + xv.y * w[q].y + xv.z * w[q].z + xv.w * w[q].w;
            }
            acc[r] = a;
        }
    }
    float bj = b[j];
    #pragma unroll
    for (int r = 0; r < PR; r++) yb[r][j] = bj + scale[r] * acc[r];
    __syncthreads();

    {
        int r = t >> 3, i = t & 7;
        float s1 = 0.f, s2 = 0.f;
        const float* yr = yb[r] + i * 16;
        #pragma unroll
        for (int c = 0; c < 16; c++) { float v = yr[c]; s1 += v; s2 += v * v; }
        s1 += __shfl_down(s1, 4, 8); s2 += __shfl_down(s2, 4, 8);
        s1 += __shfl_down(s1, 2, 8); s2 += __shfl_down(s2, 2, 8);
        s1 += __shfl_down(s1, 1, 8); s2 += __shfl_down(s2, 1, 8);
        if (i == 0) {
            float mu = s1 / D;
            float var = s2 / D - mu * mu;
            mu_s[r] = mu;
            rs_s[r] = rsqrtf(var + 1e-5f);
        }
    }
    __syncthreads();

    float gj = g[j], bej = be[j];
    #pragma unroll
    for (int r = 0; r < PR; r++) {
        float v = (yb[r][j] - mu_s[r]) * rs_s[r] * gj + bej;
        v = fmaxf(v, 0.f);
        xbuf[((rowbase + r) * 2 + p) * D + j] = v;
    }
}

// Fused MHA over P=2 + residual + LN + mean over P.
__global__ __launch_bounds__(384) void k_attn(
    const float* __restrict__ xbuf,
    const float* __restrict__ Win, const float* __restrict__ binq,
    const float* __restrict__ Wout, const float* __restrict__ bout,
    const float* __restrict__ lng, const float* __restrict__ lnb,
    float* __restrict__ out) {
    __shared__ float xs[AR][D];
    __shared__ float qkv[AR][3 * D];
    __shared__ float os[AR][D];
    __shared__ float aw[AP][4][2][2];
    __shared__ float mu_s[AR], rs_s[AR];
    int t = threadIdx.x;
    size_t pairbase = (size_t)blockIdx.x * AP;
    size_t rowbase = pairbase * 2;

    const float4* gx = (const float4*)(xbuf + rowbase * D);
    float4* sx = (float4*)&xs[0][0];
    for (int i = t; i < AR * D / 4; i += 384) sx[i] = gx[i];
    __syncthreads();

    {
        int j = t;
        float acc[AR];
        #pragma unroll
        for (int r = 0; r < AR; r++) acc[r] = 0.f;
        const float4* wrow = (const float4*)(Win + (size_t)j * D);
        #pragma unroll
        for (int kc = 0; kc < 4; kc++) {
            float4 w[8];
            #pragma unroll
            for (int q = 0; q < 8; q++) w[q] = wrow[kc * 8 + q];
            #pragma unroll
            for (int r = 0; r < AR; r++) {
                const float4* xr = (const float4*)&xs[r][kc * 32];
                float a = acc[r];
                #pragma unroll
                for (int q = 0; q < 8; q++) {
                    float4 xv = xr[q];
                    a += xv.x * w[q].x + xv.y * w[q].y + xv.z * w[q].z + xv.w * w[q].w;
                }
                acc[r] = a;
            }
        }
        float bj = binq[j];
        float sc = (j < D) ? 0.17677669529663687f : 1.0f;
        #pragma unroll
        for (int r = 0; r < AR; r++) qkv[r][j] = (acc[r] + bj) * sc;
    }
    __syncthreads();

    if (t < AP * 4) {
        int pp = t >> 2, h = t & 3;
        int r0 = pp * 2, r1 = r0 + 1;
        const float* q0 = &qkv[r0][h * 32];
        const float* q1 = &qkv[r1][h * 32];
        const float* k0 = &qkv[r0][D + h * 32];
        const float* k1 = &qkv[r1][D + h * 32];
        float s00 = 0, s01 = 0, s10 = 0, s11 = 0;
        #pragma unroll
        for (int e = 0; e < 32; e++) {
            float a0 = q0[e], a1 = q1[e], c0 = k0[e], c1 = k1[e];
            s00 += a0 * c0; s01 += a0 * c1; s10 += a1 * c0; s11 += a1 * c1;
        }
        float m0 = fmaxf(s00, s01);
        float e00 = __expf(s00 - m0), e01 = __expf(s01 - m0);
        float i0 = 1.f / (e00 + e01);
        aw[pp][h][0][0] = e00 * i0; aw[pp][h][0][1] = e01 * i0;
        float m1 = fmaxf(s10, s11);
        float e10 = __expf(s10 - m1), e11 = __expf(s11 - m1);
        float i1 = 1.f / (e10 + e11);
        aw[pp][h][1][0] = e10 * i1; aw[pp][h][1][1] = e11 * i1;
    }
    __syncthreads();

    for (int idx = t; idx < AR * D; idx += 384) {
        int r = idx >> 7;
        int j = idx & 127;
        int pp = r >> 1, pq = r & 1, h = j >> 5;
        float a0 = aw[pp][h][pq][0], a1 = aw[pp][h][pq][1];
        os[r][j] = a0 * qkv[pp * 2][2 * D + j] + a1 * qkv[pp * 2 + 1][2 * D + j];
    }
    __syncthreads();

    if (t < D) {
        int j = t;
        float acc[AR];
        #pragma unroll
        for (int r = 0; r < AR; r++) acc[r] = 0.f;
        const float4* wrow = (const float4*)(Wout + (size_t)j * D);
        #pragma unroll
        for (int kc = 0; kc < 4; kc++) {
            float4 w[8];
            #pragma unroll
            for (int q = 0; q < 8; q++) w[q] = wrow[kc * 8 + q];
            #pragma unroll
            for (int r = 0; r < AR; r++) {
                const float4* orr = (const float4*)&os[r][kc * 32];
                float a = acc[r];
                #pragma unroll
                for (int q = 0; q < 8; q++) {
                    float4 xv = orr[q];
                    a += xv.x * w[q].x + xv.y * w[q].y + xv.z * w[q].z + xv.w * w[q].w;
                }
                acc[r] = a;
            }
        }
        float bj = bout[j];
        #pragma unroll
        for (int r = 0; r < AR; r++) qkv[r][j] = acc[r] + bj + xs[r][j];
    }
    __syncthreads();

    if (t < 128) {
        int r = t >> 3, i = t & 7;
        float s1 = 0.f, s2 = 0.f;
        const float* yr = &qkv[r][i * 16];
        #pragma unroll
        for (int c = 0; c < 16; c++) { float v = yr[c]; s1 += v; s2 += v * v; }
        s1 += __shfl_down(s1, 4, 8); s2 += __shfl_down(s2, 4, 8);
        s1 += __shfl_down(s1, 2, 8); s2 += __shfl_down(s2, 2, 8);
        s1 += __shfl_down(s1, 1, 8); s2 += __shfl_down(s2, 1, 8);
        if (i == 0) {
            float mu = s1 / D;
            float var = s2 / D - mu * mu;
            mu_s[r] = mu; rs_s[r] = rsqrtf(var + 1e-5f);
        }
    }
    __syncthreads();

    if (t < 128) {
        int j = t;
        float gj = lng[j], bj = lnb[j];
        #pragma unroll
        for (int pp = 0; pp < AP; pp++) {
            int r0 = pp * 2, r1 = r0 + 1;
            float v0 = (qkv[r0][j] - mu_s[r0]) * rs_s[r0] * gj + bj;
            float v1 = (qkv[r1][j] - mu_s[r1]) * rs_s[r1] * gj + bj;
            out[(pairbase + pp) * D + j] = 0.5f * (v0 + v1);
        }
    }
}

extern "C" void kernel_launch(void* const* d_in, const int* in_sizes, int n_in,
                              void* d_out, int out_size, void* d_ws, size_t ws_size,
                              hipStream_t stream) {
    const float* feat_A = (const float*)d_in[0];
    const float* feat_B = (const float*)d_in[1];
    const int*   src_ab = (const int*)d_in[2];
    const int*   dst_ab = (const int*)d_in[3];
    const float* val_ab = (const float*)d_in[4];
    const int*   src_ba = (const int*)d_in[5];
    const int*   dst_ba = (const int*)d_in[6];
    const float* val_ba = (const float*)d_in[7];
    const float* W1 = (const float*)d_in[8];
    const float* b1 = (const float*)d_in[9];
    const float* g1 = (const float*)d_in[10];
    const float* be1 = (const float*)d_in[11];
    const float* W2 = (const float*)d_in[12];
    const float* b2 = (const float*)d_in[13];
    const float* g2 = (const float*)d_in[14];
    const float* be2 = (const float*)d_in[15];
    const float* Win = (const float*)d_in[16];
    const float* binq = (const float*)d_in[17];
    const float* Wout = (const float*)d_in[18];
    const float* bout = (const float*)d_in[19];
    const float* lng = (const float*)d_in[20];
    const float* lnb = (const float*)d_in[21];

    int E  = in_sizes[2];
    int nA = in_sizes[0] / NODE_ROW;   // 30000
    int nB = in_sizes[1] / NODE_ROW;   // 30000
    int rowsA = nA * 2;                // N_A * V

    // d_out (60000*128 floats = 30.7MB) doubles as bufB scratch (30000*256);
    // it is consumed by k_gather2 and fully overwritten by k_attn at the end.
    float* bufB  = (float*)d_out;
    float* bufA1 = (float*)d_ws;                      // [nA, 256]
    float* bufA2 = bufA1 + (size_t)nA * NODE_ROW;     // [nA, 256]
    float* xbuf  = bufA2 + (size_t)nA * NODE_ROW;     // [rowsA, 2, 128]
    int* cnt_ab   = (int*)(xbuf + (size_t)rowsA * 2 * D);
    int* cnt_ba   = cnt_ab + nB;
    int* start_ab = cnt_ba + nA;
    int* start_ba = start_ab + (nB + 1);
    uintptr_t a = (uintptr_t)(start_ba + (nA + 1));
    a = (a + 7) & ~(uintptr_t)7;
    int2* ep_ab = (int2*)a;
    int2* ep_ba = ep_ab + E;

    int egrid = (E + 255) / 256;

    // CSR build for both graphs
    hipMemsetAsync(cnt_ab, 0, (size_t)(nA + nB) * sizeof(int), stream);
    k_hist<<<egrid, 256, 0, stream>>>(dst_ab, dst_ba, cnt_ab, cnt_ba, E);
    k_scan<<<1, 1024, 0, stream>>>(cnt_ab, start_ab, nB);
    k_scan<<<1, 1024, 0, stream>>>(cnt_ba, start_ba, nA);
    hipMemsetAsync(cnt_ab, 0, (size_t)(nA + nB) * sizeof(int), stream);
    k_scatter<<<egrid, 256, 0, stream>>>(src_ab, dst_ab, val_ab,
                                         src_ba, dst_ba, val_ba,
                                         start_ab, start_ba, cnt_ab, cnt_ba,
                                         ep_ab, ep_ba, E);

    // metapath A->B (normed into bufB), then fused B->A for both operands
    k_gather_norm<<<(nB + 3) / 4, 256, 0, stream>>>(feat_A, ep_ab, start_ab, bufB, nB);
    k_gather2<<<(nA + 3) / 4, 256, 0, stream>>>(bufB, feat_B, ep_ba, start_ba,
                                                bufA1, bufA2, nA);

    // dense epilogue
    k_proj<<<rowsA / PR, 128, 0, stream>>>(bufA1, W1, b1, g1, be1, xbuf, 0);
    k_proj<<<rowsA / PR, 128, 0, stream>>>(bufA2, W2, b2, g2, be2, xbuf, 1);
    k_attn<<<rowsA / AP, 384, 0, stream>>>(xbuf, Win, binq, Wout, bout, lng, lnb,
                                           (float*)d_out);
}

// Round 4
// 741.368 us; speedup vs baseline: 7.4118x; 1.3873x over previous
//
#include <hip/hip_runtime.h>

// Problem constants: N_A=N_B=30000, V=2, D=128
#define D 128
#define NODE_ROW 256       // V*D floats per node
#define PR 16              // rows per block in k_proj
#define AP 8               // (n,v) pairs per block in k_attn2
#define AR (AP * 2)        // x-rows per block in k_attn2 (P=2)

typedef __attribute__((ext_vector_type(8))) short short8;
typedef __attribute__((ext_vector_type(4))) float floatx4;

__device__ __forceinline__ ushort f2bf(float f) {
    unsigned int u = __float_as_uint(f);
    u += 0x7fffu + ((u >> 16) & 1u);
    return (ushort)(u >> 16);
}
__device__ __forceinline__ unsigned int pk2(float a, float b) {
    return (unsigned int)f2bf(a) | ((unsigned int)f2bf(b) << 16);
}
__device__ __forceinline__ short8 ldfrag(const ushort* p) {
    union { uint4 u; short8 s; } cv;
    cv.u = *(const uint4*)p;
    return cv.s;
}

// ---------------- CSR build (verbatim R2) ----------------

__global__ __launch_bounds__(256) void k_hist(
    const int* __restrict__ dst_ab, const int* __restrict__ dst_ba,
    int* __restrict__ cnt_ab, int* __restrict__ cnt_ba, int E) {
    int i = blockIdx.x * 256 + threadIdx.x;
    if (i >= E) return;
    atomicAdd(&cnt_ab[dst_ab[i]], 1);
    atomicAdd(&cnt_ba[dst_ba[i]], 1);
}

__global__ __launch_bounds__(1024) void k_scan(
    const int* __restrict__ cnt, int* __restrict__ start, int n) {
    __shared__ int part[1024];
    int t = threadIdx.x;
    int chunk = (n + 1023) >> 10;
    int lo = min(t * chunk, n), hi = min(lo + chunk, n);
    int s = 0;
    for (int i = lo; i < hi; i++) s += cnt[i];
    part[t] = s;
    __syncthreads();
    for (int d = 1; d < 1024; d <<= 1) {
        int v = (t >= d) ? part[t - d] : 0;
        __syncthreads();
        part[t] += v;
        __syncthreads();
    }
    int off = part[t] - s;
    for (int i = lo; i < hi; i++) { start[i] = off; off += cnt[i]; }
    if (t == 1023) start[n] = off;
}

__global__ __launch_bounds__(256) void k_scatter(
    const int* __restrict__ src_ab, const int* __restrict__ dst_ab,
    const float* __restrict__ val_ab,
    const int* __restrict__ src_ba, const int* __restrict__ dst_ba,
    const float* __restrict__ val_ba,
    const int* __restrict__ start_ab, const int* __restrict__ start_ba,
    int* __restrict__ cnt_ab, int* __restrict__ cnt_ba,
    int2* __restrict__ ep_ab, int2* __restrict__ ep_ba, int E) {
    int i = blockIdx.x * 256 + threadIdx.x;
    if (i >= E) return;
    {
        int dd = dst_ab[i];
        int pos = start_ab[dd] + atomicAdd(&cnt_ab[dd], 1);
        ep_ab[pos] = make_int2(src_ab[i], __float_as_int(val_ab[i]));
    }
    {
        int dd = dst_ba[i];
        int pos = start_ba[dd] + atomicAdd(&cnt_ba[dd], 1);
        ep_ba[pos] = make_int2(src_ba[i], __float_as_int(val_ba[i]));
    }
}

// ---------------- gather SpMM (verbatim R2) ----------------

__global__ __launch_bounds__(256) void k_gather_norm(
    const float* __restrict__ feat, const int2* __restrict__ ep,
    const int* __restrict__ start, float* __restrict__ out, int n) {
    int node = blockIdx.x * 4 + (threadIdx.x >> 6);
    if (node >= n) return;
    int lane = threadIdx.x & 63;
    int lo = start[node], hi = start[node + 1];
    float4 acc = make_float4(0.f, 0.f, 0.f, 0.f);
    int i = lo;
    for (; i + 1 < hi; i += 2) {
        int2 p0 = ep[i], p1 = ep[i + 1];
        float w0 = __int_as_float(p0.y), w1 = __int_as_float(p1.y);
        float4 f0 = ((const float4*)(feat + (size_t)p0.x * NODE_ROW))[lane];
        float4 f1 = ((const float4*)(feat + (size_t)p1.x * NODE_ROW))[lane];
        acc.x += w0 * f0.x + w1 * f1.x;
        acc.y += w0 * f0.y + w1 * f1.y;
        acc.z += w0 * f0.z + w1 * f1.z;
        acc.w += w0 * f0.w + w1 * f1.w;
    }
    if (i < hi) {
        int2 p0 = ep[i];
        float w0 = __int_as_float(p0.y);
        float4 f0 = ((const float4*)(feat + (size_t)p0.x * NODE_ROW))[lane];
        acc.x += w0 * f0.x; acc.y += w0 * f0.y;
        acc.z += w0 * f0.z; acc.w += w0 * f0.w;
    }
    float ss = acc.x * acc.x + acc.y * acc.y + acc.z * acc.z + acc.w * acc.w;
    #pragma unroll
    for (int o = 16; o > 0; o >>= 1) ss += __shfl_xor(ss, o, 32);
    float sc = 1.0f / fmaxf(sqrtf(ss), 1e-12f);
    acc.x *= sc; acc.y *= sc; acc.z *= sc; acc.w *= sc;
    ((float4*)(out + (size_t)node * NODE_ROW))[lane] = acc;
}

__global__ __launch_bounds__(256) void k_gather2(
    const float* __restrict__ featP, const float* __restrict__ featQ,
    const int2* __restrict__ ep, const int* __restrict__ start,
    float* __restrict__ outP, float* __restrict__ outQ, int n) {
    int node = blockIdx.x * 4 + (threadIdx.x >> 6);
    if (node >= n) return;
    int lane = threadIdx.x & 63;
    int lo = start[node], hi = start[node + 1];
    float4 aP = make_float4(0.f, 0.f, 0.f, 0.f);
    float4 aQ = make_float4(0.f, 0.f, 0.f, 0.f);
    for (int i = lo; i < hi; i++) {
        int2 p = ep[i];
        float w = __int_as_float(p.y);
        size_t off = (size_t)p.x * NODE_ROW;
        float4 fP = ((const float4*)(featP + off))[lane];
        float4 fQ = ((const float4*)(featQ + off))[lane];
        aP.x += w * fP.x; aP.y += w * fP.y; aP.z += w * fP.z; aP.w += w * fP.w;
        aQ.x += w * fQ.x; aQ.y += w * fQ.y; aQ.z += w * fQ.z; aQ.w += w * fQ.w;
    }
    ((float4*)(outP + (size_t)node * NODE_ROW))[lane] = aP;
    ((float4*)(outQ + (size_t)node * NODE_ROW))[lane] = aQ;
}

// ---------------- weight fp32 -> bf16 pre-convert ----------------
// layout in dst: W1b[16384] | W2b[16384] | Winb[49152] | Woutb[16384]
__global__ __launch_bounds__(256) void k_cvt(
    const float* __restrict__ W1, const float* __restrict__ W2,
    const float* __restrict__ Win, const float* __restrict__ Wout,
    ushort* __restrict__ dst) {
    int idx = (blockIdx.x * 256 + threadIdx.x) * 4;
    if (idx >= 98304) return;
    const float* s; int off;
    if (idx < 16384)      { s = W1;  off = idx; }
    else if (idx < 32768) { s = W2;  off = idx - 16384; }
    else if (idx < 81920) { s = Win; off = idx - 32768; }
    else                  { s = Wout; off = idx - 81920; }
    float4 f = *(const float4*)(s + off);
    uint2 p;
    p.x = pk2(f.x, f.y);
    p.y = pk2(f.z, f.w);
    *(uint2*)(dst + idx) = p;
}

// ---------------- k_proj (verbatim R2, fp32, proven) ----------------

__global__ __launch_bounds__(128) void k_proj(
    const float* __restrict__ in, const float* __restrict__ W,
    const float* __restrict__ b, const float* __restrict__ g,
    const float* __restrict__ be, float* __restrict__ xbuf, int p) {
    __shared__ float xin[PR][D];
    __shared__ float yb[PR][D];
    __shared__ float scale[PR];
    __shared__ float mu_s[PR], rs_s[PR];
    int t = threadIdx.x;
    size_t rowbase = (size_t)blockIdx.x * PR;

    const float4* gin = (const float4*)(in + rowbase * D);
    float4* sxin = (float4*)&xin[0][0];
    for (int i = t; i < PR * D / 4; i += 128) sxin[i] = gin[i];
    __syncthreads();

    {
        int r = t >> 3, i = t & 7;
        float ss = 0.f;
        const float* xr = xin[r] + i * 16;
        #pragma unroll
        for (int c = 0; c < 16; c++) { float v = xr[c]; ss += v * v; }
        ss += __shfl_down(ss, 4, 8);
        ss += __shfl_down(ss, 2, 8);
        ss += __shfl_down(ss, 1, 8);
        if (i == 0) scale[r] = 1.0f / fmaxf(sqrtf(ss), 1e-12f);
    }
    __syncthreads();

    int j = t;
    float acc[PR];
    #pragma unroll
    for (int r = 0; r < PR; r++) acc[r] = 0.f;
    const float4* wrow = (const float4*)(W + (size_t)j * D);
    #pragma unroll
    for (int kc = 0; kc < 4; kc++) {
        float4 w[8];
        #pragma unroll
        for (int q = 0; q < 8; q++) w[q] = wrow[kc * 8 + q];
        #pragma unroll
        for (int r = 0; r < PR; r++) {
            const float4* xr = (const float4*)&xin[r][kc * 32];
            float a = acc[r];
            #pragma unroll
            for (int q = 0; q < 8; q++) {
                float4 xv = xr[q];
                a += xv.x * w[q].x + xv.y * w[q].y + xv.z * w[q].z + xv.w * w[q].w;
            }
            acc[r] = a;
        }
    }
    float bj = b[j];
    #pragma unroll
    for (int r = 0; r < PR; r++) yb[r][j] = bj + scale[r] * acc[r];
    __syncthreads();

    {
        int r = t >> 3, i = t & 7;
        float s1 = 0.f, s2 = 0.f;
        const float* yr = yb[r] + i * 16;
        #pragma unroll
        for (int c = 0; c < 16; c++) { float v = yr[c]; s1 += v; s2 += v * v; }
        s1 += __shfl_down(s1, 4, 8); s2 += __shfl_down(s2, 4, 8);
        s1 += __shfl_down(s1, 2, 8); s2 += __shfl_down(s2, 2, 8);
        s1 += __shfl_down(s1, 1, 8); s2 += __shfl_down(s2, 1, 8);
        if (i == 0) {
            float mu = s1 / D;
            float var = s2 / D - mu * mu;
            mu_s[r] = mu;
            rs_s[r] = rsqrtf(var + 1e-5f);
        }
    }
    __syncthreads();

    float gj = g[j], bej = be[j];
    #pragma unroll
    for (int r = 0; r < PR; r++) {
        float v = (yb[r][j] - mu_s[r]) * rs_s[r] * gj + bej;
        v = fmaxf(v, 0.f);
        xbuf[((rowbase + r) * 2 + p) * D + j] = v;
    }
}

// ---------------- k_attn2: R2 dataflow, MFMA for QKV & Wout GEMMs ----------------
// All intermediates fp32 (as in passing R2); bf16 only for MFMA operands.
__global__ __launch_bounds__(384) void k_attn2(
    const float* __restrict__ xbuf,
    const ushort* __restrict__ Winb, const float* __restrict__ binq,
    const ushort* __restrict__ Woutb, const float* __restrict__ bout,
    const float* __restrict__ lng, const float* __restrict__ lnb,
    float* __restrict__ out) {
    __shared__ float xs[AR][D];        // x rows (residual), fp32
    __shared__ float qkv[AR][3 * D];   // fp32; cols 0..127 reused as y
    __shared__ float os[AR][D];        // attention output o, fp32
    __shared__ float aw[AP][4][2][2];
    __shared__ float mu_s[AR], rs_s[AR];
    __shared__ ushort xb[AR][136];     // bf16 copy of xs (MFMA A-operand)
    __shared__ ushort ob[AR][136];     // bf16 copy of os (MFMA A-operand)
    int t = threadIdx.x;
    int lane = t & 63, w = t >> 6;
    int c = lane & 15, quad = lane >> 4;
    size_t pairbase = (size_t)blockIdx.x * AP;
    size_t rowbase = pairbase * 2;

    // load xs (fp32) + pack xb (bf16)
    const float4* gx = (const float4*)(xbuf + rowbase * D);
    float4* sx = (float4*)&xs[0][0];
    for (int i = t; i < AR * D / 4; i += 384) {
        float4 v = gx[i];
        sx[i] = v;
        int r = i >> 5;             // 32 float4 per 128-row
        int col = (i & 31) * 4;
        ushort* xp = &xb[r][col];
        xp[0] = f2bf(v.x); xp[1] = f2bf(v.y);
        xp[2] = f2bf(v.z); xp[3] = f2bf(v.w);
    }
    __syncthreads();

    // QKV GEMM via MFMA: M=16 (one tile), N=384 (wave w -> ntiles w*4..w*4+3)
    {
        short8 af[4];
        #pragma unroll
        for (int kt = 0; kt < 4; kt++)
            af[kt] = ldfrag(&xb[c][kt * 32 + quad * 8]);
        #pragma unroll
        for (int nt2 = 0; nt2 < 4; nt2++) {
            int j = (w * 4 + nt2) * 16 + c;
            floatx4 acc = {0.f, 0.f, 0.f, 0.f};
            #pragma unroll
            for (int kt = 0; kt < 4; kt++) {
                short8 bfr = ldfrag(Winb + (size_t)j * 128 + kt * 32 + quad * 8);
                acc = __builtin_amdgcn_mfma_f32_16x16x32_bf16(af[kt], bfr, acc, 0, 0, 0);
            }
            float bj = binq[j];
            float sc = (j < 128) ? 0.17677669529663687f : 1.0f;
            #pragma unroll
            for (int rg = 0; rg < 4; rg++)
                qkv[quad * 4 + rg][j] = (acc[rg] + bj) * sc;
        }
    }
    __syncthreads();

    // scores (2x2 per head) + softmax — VERBATIM R2, fp32
    if (t < AP * 4) {
        int pp = t >> 2, h = t & 3;
        int r0 = pp * 2, r1 = r0 + 1;
        const float* q0 = &qkv[r0][h * 32];
        const float* q1 = &qkv[r1][h * 32];
        const float* k0 = &qkv[r0][D + h * 32];
        const float* k1 = &qkv[r1][D + h * 32];
        float s00 = 0, s01 = 0, s10 = 0, s11 = 0;
        #pragma unroll
        for (int e = 0; e < 32; e++) {
            float a0 = q0[e], a1 = q1[e], c0 = k0[e], c1 = k1[e];
            s00 += a0 * c0; s01 += a0 * c1; s10 += a1 * c0; s11 += a1 * c1;
        }
        float m0 = fmaxf(s00, s01);
        float e00 = __expf(s00 - m0), e01 = __expf(s01 - m0);
        float i0 = 1.f / (e00 + e01);
        aw[pp][h][0][0] = e00 * i0; aw[pp][h][0][1] = e01 * i0;
        float m1 = fmaxf(s10, s11);
        float e10 = __expf(s10 - m1), e11 = __expf(s11 - m1);
        float i1 = 1.f / (e10 + e11);
        aw[pp][h][1][0] = e10 * i1; aw[pp][h][1][1] = e11 * i1;
    }
    __syncthreads();

    // o = a @ v — VERBATIM R2, fp32
    for (int idx = t; idx < AR * D; idx += 384) {
        int r = idx >> 7;
        int j = idx & 127;
        int pp = r >> 1, pq = r & 1, h = j >> 5;
        float a0 = aw[pp][h][pq][0], a1 = aw[pp][h][pq][1];
        os[r][j] = a0 * qkv[pp * 2][2 * D + j] + a1 * qkv[pp * 2 + 1][2 * D + j];
    }
    __syncthreads();

    // pack ob (bf16) from os
    for (int i = t; i < AR * D / 4; i += 384) {
        int r = i >> 5;
        int col = (i & 31) * 4;
        float4 v = ((const float4*)&os[0][0])[i];
        ushort* op = &ob[r][col];
        op[0] = f2bf(v.x); op[1] = f2bf(v.y);
        op[2] = f2bf(v.z); op[3] = f2bf(v.w);
    }
    __syncthreads();

    // out-proj via MFMA + bias + residual -> qkv[r][j] (cols 0..127)
    if (w < 4) {
        short8 af[4];
        #pragma unroll
        for (int kt = 0; kt < 4; kt++)
            af[kt] = ldfrag(&ob[c][kt * 32 + quad * 8]);
        #pragma unroll
        for (int nt2 = 0; nt2 < 2; nt2++) {
            int j = (w * 2 + nt2) * 16 + c;
            floatx4 acc = {0.f, 0.f, 0.f, 0.f};
            #pragma unroll
            for (int kt = 0; kt < 4; kt++) {
                short8 bfr = ldfrag(Woutb + (size_t)j * 128 + kt * 32 + quad * 8);
                acc = __builtin_amdgcn_mfma_f32_16x16x32_bf16(af[kt], bfr, acc, 0, 0, 0);
            }
            float bj = bout[j];
            #pragma unroll
            for (int rg = 0; rg < 4; rg++) {
                int row = quad * 4 + rg;
                qkv[row][j] = acc[rg] + bj + xs[row][j];
            }
        }
    }
    __syncthreads();

    // LN stats per row — VERBATIM R2
    if (t < 128) {
        int r = t >> 3, i = t & 7;
        float s1 = 0.f, s2 = 0.f;
        const float* yr = &qkv[r][i * 16];
        #pragma unroll
        for (int cc = 0; cc < 16; cc++) { float v = yr[cc]; s1 += v; s2 += v * v; }
        s1 += __shfl_down(s1, 4, 8); s2 += __shfl_down(s2, 4, 8);
        s1 += __shfl_down(s1, 2, 8); s2 += __shfl_down(s2, 2, 8);
        s1 += __shfl_down(s1, 1, 8); s2 += __shfl_down(s2, 1, 8);
        if (i == 0) {
            float mu = s1 / D;
            float var = s2 / D - mu * mu;
            mu_s[r] = mu; rs_s[r] = rsqrtf(var + 1e-5f);
        }
    }
    __syncthreads();

    // LN apply + mean over P — VERBATIM R2
    if (t < 128) {
        int j = t;
        float gj = lng[j], bj = lnb[j];
        #pragma unroll
        for (int pp = 0; pp < AP; pp++) {
            int r0 = pp * 2, r1 = r0 + 1;
            float v0 = (qkv[r0][j] - mu_s[r0]) * rs_s[r0] * gj + bj;
            float v1 = (qkv[r1][j] - mu_s[r1]) * rs_s[r1] * gj + bj;
            out[(pairbase + pp) * D + j] = 0.5f * (v0 + v1);
        }
    }
}

extern "C" void kernel_launch(void* const* d_in, const int* in_sizes, int n_in,
                              void* d_out, int out_size, void* d_ws, size_t ws_size,
                              hipStream_t stream) {
    const float* feat_A = (const float*)d_in[0];
    const float* feat_B = (const float*)d_in[1];
    const int*   src_ab = (const int*)d_in[2];
    const int*   dst_ab = (const int*)d_in[3];
    const float* val_ab = (const float*)d_in[4];
    const int*   src_ba = (const int*)d_in[5];
    const int*   dst_ba = (const int*)d_in[6];
    const float* val_ba = (const float*)d_in[7];
    const float* W1 = (const float*)d_in[8];
    const float* b1 = (const float*)d_in[9];
    const float* g1 = (const float*)d_in[10];
    const float* be1 = (const float*)d_in[11];
    const float* W2 = (const float*)d_in[12];
    const float* b2 = (const float*)d_in[13];
    const float* g2 = (const float*)d_in[14];
    const float* be2 = (const float*)d_in[15];
    const float* Win = (const float*)d_in[16];
    const float* binq = (const float*)d_in[17];
    const float* Wout = (const float*)d_in[18];
    const float* bout = (const float*)d_in[19];
    const float* lng = (const float*)d_in[20];
    const float* lnb = (const float*)d_in[21];

    int E  = in_sizes[2];
    int nA = in_sizes[0] / NODE_ROW;   // 30000
    int nB = in_sizes[1] / NODE_ROW;   // 30000
    int rowsA = nA * 2;                // N_A * V = 60000

    // Workspace layout — identical footprint to passing R2 (+ Wbf aliases cnt_*)
    float* bufB  = (float*)d_out;                     // d_out doubles as scratch
    float* bufA1 = (float*)d_ws;                      // [nA, 256]
    float* bufA2 = bufA1 + (size_t)nA * NODE_ROW;     // [nA, 256]
    float* xbuf  = bufA2 + (size_t)nA * NODE_ROW;     // [rowsA, 2, 128]
    int* cnt_ab   = (int*)(xbuf + (size_t)rowsA * 2 * D);
    int* cnt_ba   = cnt_ab + nB;
    int* start_ab = cnt_ba + nA;
    int* start_ba = start_ab + (nB + 1);
    uintptr_t a = (uintptr_t)(start_ba + (nA + 1));
    a = (a + 15) & ~(uintptr_t)15;
    int2* ep_ab = (int2*)a;
    int2* ep_ba = ep_ab + E;
    // Wbf reuses the cnt_ab/cnt_ba region (240000 B >= 196608 B needed),
    // written by k_cvt strictly after k_scatter's last use of the counts.
    ushort* Wbf   = (ushort*)cnt_ab;
    ushort* Winb  = Wbf + 32768;
    ushort* Woutb = Wbf + 81920;

    int egrid = (E + 255) / 256;

    // CSR build for both graphs
    hipMemsetAsync(cnt_ab, 0, (size_t)(nA + nB) * sizeof(int), stream);
    k_hist<<<egrid, 256, 0, stream>>>(dst_ab, dst_ba, cnt_ab, cnt_ba, E);
    k_scan<<<1, 1024, 0, stream>>>(cnt_ab, start_ab, nB);
    k_scan<<<1, 1024, 0, stream>>>(cnt_ba, start_ba, nA);
    hipMemsetAsync(cnt_ab, 0, (size_t)(nA + nB) * sizeof(int), stream);
    k_scatter<<<egrid, 256, 0, stream>>>(src_ab, dst_ab, val_ab,
                                         src_ba, dst_ba, val_ba,
                                         start_ab, start_ba, cnt_ab, cnt_ba,
                                         ep_ab, ep_ba, E);

    // weights -> bf16 (overwrites dead cnt region)
    k_cvt<<<96, 256, 0, stream>>>(W1, W2, Win, Wout, Wbf);

    // metapath aggregations
    k_gather_norm<<<(nB + 3) / 4, 256, 0, stream>>>(feat_A, ep_ab, start_ab, bufB, nB);
    k_gather2<<<(nA + 3) / 4, 256, 0, stream>>>(bufB, feat_B, ep_ba, start_ba,
                                                bufA1, bufA2, nA);

    // dense epilogue: proven fp32 proj, MFMA-accelerated attention
    k_proj<<<rowsA / PR, 128, 0, stream>>>(bufA1, W1, b1, g1, be1, xbuf, 0);
    k_proj<<<rowsA / PR, 128, 0, stream>>>(bufA2, W2, b2, g2, be2, xbuf, 1);
    k_attn2<<<rowsA / AP, 384, 0, stream>>>(xbuf, Winb, binq, Woutb, bout,
                                            lng, lnb, (float*)d_out);
}

// Round 5
// 648.302 us; speedup vs baseline: 8.4758x; 1.1436x over previous
//
#include <hip/hip_runtime.h>

// Problem constants: N_A=N_B=30000, V=2, D=128
#define D 128
#define NODE_ROW 256       // V*D elements per node
#define AP 8               // (n,v) pairs per block in k_attn2
#define AR (AP * 2)        // x-rows per block in k_attn2 (P=2)

typedef __attribute__((ext_vector_type(8))) short short8;
typedef __attribute__((ext_vector_type(4))) float floatx4;

__device__ __forceinline__ ushort f2bf(float f) {
    unsigned int u = __float_as_uint(f);
    u += 0x7fffu + ((u >> 16) & 1u);
    return (ushort)(u >> 16);
}
__device__ __forceinline__ unsigned int pk2(float a, float b) {
    return (unsigned int)f2bf(a) | ((unsigned int)f2bf(b) << 16);
}
__device__ __forceinline__ void up8(uint4 u, float* f) {
    f[0] = __uint_as_float(u.x << 16); f[1] = __uint_as_float(u.x & 0xffff0000u);
    f[2] = __uint_as_float(u.y << 16); f[3] = __uint_as_float(u.y & 0xffff0000u);
    f[4] = __uint_as_float(u.z << 16); f[5] = __uint_as_float(u.z & 0xffff0000u);
    f[6] = __uint_as_float(u.w << 16); f[7] = __uint_as_float(u.w & 0xffff0000u);
}
__device__ __forceinline__ short8 ldfrag(const ushort* p) {
    union { uint4 u; short8 s; } cv;
    cv.u = *(const uint4*)p;
    return cv.s;
}

// ---------------- fp32 -> bf16 feature convert ----------------
__global__ __launch_bounds__(256) void k_f2b(
    const float* __restrict__ src, ushort* __restrict__ dst, int n8) {
    int i = blockIdx.x * 256 + threadIdx.x;
    if (i >= n8) return;
    const float4* s = (const float4*)src + (size_t)i * 2;
    float4 a = s[0], b = s[1];
    uint4 o;
    o.x = pk2(a.x, a.y); o.y = pk2(a.z, a.w);
    o.z = pk2(b.x, b.y); o.w = pk2(b.z, b.w);
    ((uint4*)dst)[i] = o;
}

// ---------------- CSR build (verbatim R2) ----------------

__global__ __launch_bounds__(256) void k_hist(
    const int* __restrict__ dst_ab, const int* __restrict__ dst_ba,
    int* __restrict__ cnt_ab, int* __restrict__ cnt_ba, int E) {
    int i = blockIdx.x * 256 + threadIdx.x;
    if (i >= E) return;
    atomicAdd(&cnt_ab[dst_ab[i]], 1);
    atomicAdd(&cnt_ba[dst_ba[i]], 1);
}

__global__ __launch_bounds__(1024) void k_scan(
    const int* __restrict__ cnt, int* __restrict__ start, int n) {
    __shared__ int part[1024];
    int t = threadIdx.x;
    int chunk = (n + 1023) >> 10;
    int lo = min(t * chunk, n), hi = min(lo + chunk, n);
    int s = 0;
    for (int i = lo; i < hi; i++) s += cnt[i];
    part[t] = s;
    __syncthreads();
    for (int d = 1; d < 1024; d <<= 1) {
        int v = (t >= d) ? part[t - d] : 0;
        __syncthreads();
        part[t] += v;
        __syncthreads();
    }
    int off = part[t] - s;
    for (int i = lo; i < hi; i++) { start[i] = off; off += cnt[i]; }
    if (t == 1023) start[n] = off;
}

__global__ __launch_bounds__(256) void k_scatter(
    const int* __restrict__ src_ab, const int* __restrict__ dst_ab,
    const float* __restrict__ val_ab,
    const int* __restrict__ src_ba, const int* __restrict__ dst_ba,
    const float* __restrict__ val_ba,
    const int* __restrict__ start_ab, const int* __restrict__ start_ba,
    int* __restrict__ cnt_ab, int* __restrict__ cnt_ba,
    int2* __restrict__ ep_ab, int2* __restrict__ ep_ba, int E) {
    int i = blockIdx.x * 256 + threadIdx.x;
    if (i >= E) return;
    {
        int dd = dst_ab[i];
        int pos = start_ab[dd] + atomicAdd(&cnt_ab[dd], 1);
        ep_ab[pos] = make_int2(src_ab[i], __float_as_int(val_ab[i]));
    }
    {
        int dd = dst_ba[i];
        int pos = start_ba[dd] + atomicAdd(&cnt_ba[dd], 1);
        ep_ba[pos] = make_int2(src_ba[i], __float_as_int(val_ba[i]));
    }
}

// ---------------- bf16 gather SpMM ----------------
// out[node] = l2norm_per_view( sum val*feat[src] ), bf16 in/out, fp32 acc
__global__ __launch_bounds__(256) void k_gather_norm_bf(
    const ushort* __restrict__ feat, const int2* __restrict__ ep,
    const int* __restrict__ start, ushort* __restrict__ out, int n) {
    int node = blockIdx.x * 4 + (threadIdx.x >> 6);
    if (node >= n) return;
    int lane = threadIdx.x & 63;
    int lo = start[node], hi = start[node + 1];
    float4 acc = make_float4(0.f, 0.f, 0.f, 0.f);
    for (int i = lo; i < hi; i++) {
        int2 p = ep[i];
        float w = __int_as_float(p.y);
        uint2 u = ((const uint2*)(feat + (size_t)p.x * NODE_ROW))[lane];
        acc.x += w * __uint_as_float(u.x << 16);
        acc.y += w * __uint_as_float(u.x & 0xffff0000u);
        acc.z += w * __uint_as_float(u.y << 16);
        acc.w += w * __uint_as_float(u.y & 0xffff0000u);
    }
    float ss = acc.x * acc.x + acc.y * acc.y + acc.z * acc.z + acc.w * acc.w;
    #pragma unroll
    for (int o = 16; o > 0; o >>= 1) ss += __shfl_xor(ss, o, 32);
    float sc = 1.0f / fmaxf(sqrtf(ss), 1e-12f);
    uint2 o;
    o.x = pk2(acc.x * sc, acc.y * sc);
    o.y = pk2(acc.z * sc, acc.w * sc);
    ((uint2*)(out + (size_t)node * NODE_ROW))[lane] = o;
}

// fused dual gather: outP = spmm(featP), outQ = spmm(featQ); bf16 in/out
__global__ __launch_bounds__(256) void k_gather2_bf(
    const ushort* __restrict__ featP, const ushort* __restrict__ featQ,
    const int2* __restrict__ ep, const int* __restrict__ start,
    ushort* __restrict__ outP, ushort* __restrict__ outQ, int n) {
    int node = blockIdx.x * 4 + (threadIdx.x >> 6);
    if (node >= n) return;
    int lane = threadIdx.x & 63;
    int lo = start[node], hi = start[node + 1];
    float4 aP = make_float4(0.f, 0.f, 0.f, 0.f);
    float4 aQ = make_float4(0.f, 0.f, 0.f, 0.f);
    for (int i = lo; i < hi; i++) {
        int2 p = ep[i];
        float w = __int_as_float(p.y);
        size_t off = (size_t)p.x * NODE_ROW;
        uint2 uP = ((const uint2*)(featP + off))[lane];
        uint2 uQ = ((const uint2*)(featQ + off))[lane];
        aP.x += w * __uint_as_float(uP.x << 16);
        aP.y += w * __uint_as_float(uP.x & 0xffff0000u);
        aP.z += w * __uint_as_float(uP.y << 16);
        aP.w += w * __uint_as_float(uP.y & 0xffff0000u);
        aQ.x += w * __uint_as_float(uQ.x << 16);
        aQ.y += w * __uint_as_float(uQ.x & 0xffff0000u);
        aQ.z += w * __uint_as_float(uQ.y << 16);
        aQ.w += w * __uint_as_float(uQ.y & 0xffff0000u);
    }
    uint2 oP, oQ;
    oP.x = pk2(aP.x, aP.y); oP.y = pk2(aP.z, aP.w);
    oQ.x = pk2(aQ.x, aQ.y); oQ.y = pk2(aQ.z, aQ.w);
    ((uint2*)(outP + (size_t)node * NODE_ROW))[lane] = oP;
    ((uint2*)(outQ + (size_t)node * NODE_ROW))[lane] = oQ;
}

// ---------------- weight fp32 -> bf16 pre-convert ----------------
// layout in dst: W1b[16384] | W2b[16384] | Winb[49152] | Woutb[16384]
__global__ __launch_bounds__(256) void k_cvt(
    const float* __restrict__ W1, const float* __restrict__ W2,
    const float* __restrict__ Win, const float* __restrict__ Wout,
    ushort* __restrict__ dst) {
    int idx = (blockIdx.x * 256 + threadIdx.x) * 4;
    if (idx >= 98304) return;
    const float* s; int off;
    if (idx < 16384)      { s = W1;  off = idx; }
    else if (idx < 32768) { s = W2;  off = idx - 16384; }
    else if (idx < 81920) { s = Win; off = idx - 32768; }
    else                  { s = Wout; off = idx - 81920; }
    float4 f = *(const float4*)(s + off);
    uint2 p;
    p.x = pk2(f.x, f.y);
    p.y = pk2(f.z, f.w);
    *(uint2*)(dst + idx) = p;
}

// ---------------- k_projm: l2norm -> MFMA GEMM -> LN -> ReLU (bf16 io) ----------------
// 16 rows per 128-thread block; MFMA pattern identical to R4's proven QKV.
__global__ __launch_bounds__(128) void k_projm(
    const ushort* __restrict__ in, const ushort* __restrict__ Wb,
    const float* __restrict__ b, const float* __restrict__ g,
    const float* __restrict__ be, ushort* __restrict__ xbuf, int p) {
    __shared__ ushort xn[16][136];
    __shared__ float yb[16][128];
    int t = threadIdx.x;
    size_t rowbase = (size_t)blockIdx.x * 16;
    int r = t >> 3, i = t & 7;     // 8 threads per row, 16 cols each

    // Phase A: load bf16 row, l2 scale (fp32), pack scaled bf16 into xn
    {
        const ushort* gp = in + (rowbase + r) * D + i * 16;
        float v[16];
        up8(((const uint4*)gp)[0], v);
        up8(((const uint4*)gp)[1], v + 8);
        float ss = 0.f;
        #pragma unroll
        for (int e = 0; e < 16; e++) ss += v[e] * v[e];
        ss += __shfl_xor(ss, 1, 8);
        ss += __shfl_xor(ss, 2, 8);
        ss += __shfl_xor(ss, 4, 8);
        float sc = 1.0f / fmaxf(sqrtf(ss), 1e-12f);
        uint4 w0, w1;
        w0.x = pk2(v[0]*sc, v[1]*sc);   w0.y = pk2(v[2]*sc, v[3]*sc);
        w0.z = pk2(v[4]*sc, v[5]*sc);   w0.w = pk2(v[6]*sc, v[7]*sc);
        w1.x = pk2(v[8]*sc, v[9]*sc);   w1.y = pk2(v[10]*sc, v[11]*sc);
        w1.z = pk2(v[12]*sc, v[13]*sc); w1.w = pk2(v[14]*sc, v[15]*sc);
        ushort* dst = &xn[r][i * 16];
        ((uint4*)dst)[0] = w0;
        ((uint4*)dst)[1] = w1;
    }
    __syncthreads();

    // Phase B: GEMM via MFMA. M=16, N=128 (wave w -> ntiles w*4..w*4+3), K=128
    {
        int lane = t & 63, w = t >> 6, c = lane & 15, quad = lane >> 4;
        short8 af[4];
        #pragma unroll
        for (int kt = 0; kt < 4; kt++)
            af[kt] = ldfrag(&xn[c][kt * 32 + quad * 8]);
        #pragma unroll
        for (int nt2 = 0; nt2 < 4; nt2++) {
            int j = (w * 4 + nt2) * 16 + c;
            floatx4 acc = {0.f, 0.f, 0.f, 0.f};
            #pragma unroll
            for (int kt = 0; kt < 4; kt++) {
                short8 bfr = ldfrag(Wb + (size_t)j * 128 + kt * 32 + quad * 8);
                acc = __builtin_amdgcn_mfma_f32_16x16x32_bf16(af[kt], bfr, acc, 0, 0, 0);
            }
            float bj = b[j];
            #pragma unroll
            for (int rg = 0; rg < 4; rg++)
                yb[quad * 4 + rg][j] = acc[rg] + bj;
        }
    }
    __syncthreads();

    // Phase C: LayerNorm (fp32) + ReLU, pack bf16 -> xbuf slot (row*2+p)
    {
        float v[16];
        const float* yr = &yb[r][i * 16];
        #pragma unroll
        for (int e = 0; e < 16; e++) v[e] = yr[e];
        float s1 = 0.f, s2 = 0.f;
        #pragma unroll
        for (int e = 0; e < 16; e++) { s1 += v[e]; s2 += v[e] * v[e]; }
        s1 += __shfl_xor(s1, 1, 8); s2 += __shfl_xor(s2, 1, 8);
        s1 += __shfl_xor(s1, 2, 8); s2 += __shfl_xor(s2, 2, 8);
        s1 += __shfl_xor(s1, 4, 8); s2 += __shfl_xor(s2, 4, 8);
        float mu = s1 * (1.0f / 128.0f);
        float var = s2 * (1.0f / 128.0f) - mu * mu;
        float rs = rsqrtf(var + 1e-5f);
        const float* gg = g + i * 16;
        const float* bb = be + i * 16;
        float res[16];
        #pragma unroll
        for (int e = 0; e < 16; e++)
            res[e] = fmaxf((v[e] - mu) * rs * gg[e] + bb[e], 0.f);
        ushort* op = xbuf + ((rowbase + r) * 2 + p) * D + i * 16;
        uint4 w0, w1;
        w0.x = pk2(res[0], res[1]);   w0.y = pk2(res[2], res[3]);
        w0.z = pk2(res[4], res[5]);   w0.w = pk2(res[6], res[7]);
        w1.x = pk2(res[8], res[9]);   w1.y = pk2(res[10], res[11]);
        w1.z = pk2(res[12], res[13]); w1.w = pk2(res[14], res[15]);
        ((uint4*)op)[0] = w0;
        ((uint4*)op)[1] = w1;
    }
}

// ---------------- k_attn2: R4-proven core, bf16 xbuf input ----------------
__global__ __launch_bounds__(384) void k_attn2(
    const ushort* __restrict__ xbuf,
    const ushort* __restrict__ Winb, const float* __restrict__ binq,
    const ushort* __restrict__ Woutb, const float* __restrict__ bout,
    const float* __restrict__ lng, const float* __restrict__ lnb,
    float* __restrict__ out) {
    __shared__ float xs[AR][D];        // x rows (residual), fp32
    __shared__ float qkv[AR][3 * D];   // fp32; cols 0..127 reused as y
    __shared__ float os[AR][D];        // attention output o, fp32
    __shared__ float aw[AP][4][2][2];
    __shared__ float mu_s[AR], rs_s[AR];
    __shared__ ushort xb[AR][136];     // bf16 copy of xs (MFMA A-operand)
    __shared__ ushort ob[AR][136];     // bf16 copy of os (MFMA A-operand)
    int t = threadIdx.x;
    int lane = t & 63, w = t >> 6;
    int c = lane & 15, quad = lane >> 4;
    size_t pairbase = (size_t)blockIdx.x * AP;
    size_t rowbase = pairbase * 2;

    // load bf16 x: raw into xb, unpacked fp32 into xs
    const uint2* gx = (const uint2*)(xbuf + rowbase * D);
    for (int i = t; i < AR * D / 4; i += 384) {
        uint2 u = gx[i];
        int r = i >> 5;             // 32 groups of 4 per 128-row
        int col = (i & 31) * 4;
        *(uint2*)&xb[r][col] = u;
        float4 v;
        v.x = __uint_as_float(u.x << 16);
        v.y = __uint_as_float(u.x & 0xffff0000u);
        v.z = __uint_as_float(u.y << 16);
        v.w = __uint_as_float(u.y & 0xffff0000u);
        *(float4*)&xs[r][col] = v;
    }
    __syncthreads();

    // QKV GEMM via MFMA: M=16, N=384 (wave w -> ntiles w*4..w*4+3)
    {
        short8 af[4];
        #pragma unroll
        for (int kt = 0; kt < 4; kt++)
            af[kt] = ldfrag(&xb[c][kt * 32 + quad * 8]);
        #pragma unroll
        for (int nt2 = 0; nt2 < 4; nt2++) {
            int j = (w * 4 + nt2) * 16 + c;
            floatx4 acc = {0.f, 0.f, 0.f, 0.f};
            #pragma unroll
            for (int kt = 0; kt < 4; kt++) {
                short8 bfr = ldfrag(Winb + (size_t)j * 128 + kt * 32 + quad * 8);
                acc = __builtin_amdgcn_mfma_f32_16x16x32_bf16(af[kt], bfr, acc, 0, 0, 0);
            }
            float bj = binq[j];
            float sc = (j < 128) ? 0.17677669529663687f : 1.0f;
            #pragma unroll
            for (int rg = 0; rg < 4; rg++)
                qkv[quad * 4 + rg][j] = (acc[rg] + bj) * sc;
        }
    }
    __syncthreads();

    // scores (2x2 per head) + softmax — fp32
    if (t < AP * 4) {
        int pp = t >> 2, h = t & 3;
        int r0 = pp * 2, r1 = r0 + 1;
        const float* q0 = &qkv[r0][h * 32];
        const float* q1 = &qkv[r1][h * 32];
        const float* k0 = &qkv[r0][D + h * 32];
        const float* k1 = &qkv[r1][D + h * 32];
        float s00 = 0, s01 = 0, s10 = 0, s11 = 0;
        #pragma unroll
        for (int e = 0; e < 32; e++) {
            float a0 = q0[e], a1 = q1[e], c0 = k0[e], c1 = k1[e];
            s00 += a0 * c0; s01 += a0 * c1; s10 += a1 * c0; s11 += a1 * c1;
        }
        float m0 = fmaxf(s00, s01);
        float e00 = __expf(s00 - m0), e01 = __expf(s01 - m0);
        float i0 = 1.f / (e00 + e01);
        aw[pp][h][0][0] = e00 * i0; aw[pp][h][0][1] = e01 * i0;
        float m1 = fmaxf(s10, s11);
        float e10 = __expf(s10 - m1), e11 = __expf(s11 - m1);
        float i1 = 1.f / (e10 + e11);
        aw[pp][h][1][0] = e10 * i1; aw[pp][h][1][1] = e11 * i1;
    }
    __syncthreads();

    // o = a @ v — fp32
    for (int idx = t; idx < AR * D; idx += 384) {
        int r = idx >> 7;
        int j = idx & 127;
        int pp = r >> 1, pq = r & 1, h = j >> 5;
        float a0 = aw[pp][h][pq][0], a1 = aw[pp][h][pq][1];
        os[r][j] = a0 * qkv[pp * 2][2 * D + j] + a1 * qkv[pp * 2 + 1][2 * D + j];
    }
    __syncthreads();

    // pack ob (bf16) from os
    for (int i = t; i < AR * D / 4; i += 384) {
        int r = i >> 5;
        int col = (i & 31) * 4;
        float4 v = ((const float4*)&os[0][0])[i];
        ushort* op = &ob[r][col];
        op[0] = f2bf(v.x); op[1] = f2bf(v.y);
        op[2] = f2bf(v.z); op[3] = f2bf(v.w);
    }
    __syncthreads();

    // out-proj via MFMA + bias + residual -> qkv[r][j] (cols 0..127)
    if (w < 4) {
        short8 af[4];
        #pragma unroll
        for (int kt = 0; kt < 4; kt++)
            af[kt] = ldfrag(&ob[c][kt * 32 + quad * 8]);
        #pragma unroll
        for (int nt2 = 0; nt2 < 2; nt2++) {
            int j = (w * 2 + nt2) * 16 + c;
            floatx4 acc = {0.f, 0.f, 0.f, 0.f};
            #pragma unroll
            for (int kt = 0; kt < 4; kt++) {
                short8 bfr = ldfrag(Woutb + (size_t)j * 128 + kt * 32 + quad * 8);
                acc = __builtin_amdgcn_mfma_f32_16x16x32_bf16(af[kt], bfr, acc, 0, 0, 0);
            }
            float bj = bout[j];
            #pragma unroll
            for (int rg = 0; rg < 4; rg++) {
                int row = quad * 4 + rg;
                qkv[row][j] = acc[rg] + bj + xs[row][j];
            }
        }
    }
    __syncthreads();

    // LN stats per row
    if (t < 128) {
        int r = t >> 3, i = t & 7;
        float s1 = 0.f, s2 = 0.f;
        const float* yr = &qkv[r][i * 16];
        #pragma unroll
        for (int cc = 0; cc < 16; cc++) { float v = yr[cc]; s1 += v; s2 += v * v; }
        s1 += __shfl_down(s1, 4, 8); s2 += __shfl_down(s2, 4, 8);
        s1 += __shfl_down(s1, 2, 8); s2 += __shfl_down(s2, 2, 8);
        s1 += __shfl_down(s1, 1, 8); s2 += __shfl_down(s2, 1, 8);
        if (i == 0) {
            float mu = s1 / D;
            float var = s2 / D - mu * mu;
            mu_s[r] = mu; rs_s[r] = rsqrtf(var + 1e-5f);
        }
    }
    __syncthreads();

    // LN apply + mean over P
    if (t < 128) {
        int j = t;
        float gj = lng[j], bj = lnb[j];
        #pragma unroll
        for (int pp = 0; pp < AP; pp++) {
            int r0 = pp * 2, r1 = r0 + 1;
            float v0 = (qkv[r0][j] - mu_s[r0]) * rs_s[r0] * gj + bj;
            float v1 = (qkv[r1][j] - mu_s[r1]) * rs_s[r1] * gj + bj;
            out[(pairbase + pp) * D + j] = 0.5f * (v0 + v1);
        }
    }
}

extern "C" void kernel_launch(void* const* d_in, const int* in_sizes, int n_in,
                              void* d_out, int out_size, void* d_ws, size_t ws_size,
                              hipStream_t stream) {
    const float* feat_A = (const float*)d_in[0];
    const float* feat_B = (const float*)d_in[1];
    const int*   src_ab = (const int*)d_in[2];
    const int*   dst_ab = (const int*)d_in[3];
    const float* val_ab = (const float*)d_in[4];
    const int*   src_ba = (const int*)d_in[5];
    const int*   dst_ba = (const int*)d_in[6];
    const float* val_ba = (const float*)d_in[7];
    const float* W1 = (const float*)d_in[8];
    const float* b1 = (const float*)d_in[9];
    const float* g1 = (const float*)d_in[10];
    const float* be1 = (const float*)d_in[11];
    const float* W2 = (const float*)d_in[12];
    const float* b2 = (const float*)d_in[13];
    const float* g2 = (const float*)d_in[14];
    const float* be2 = (const float*)d_in[15];
    const float* Win = (const float*)d_in[16];
    const float* binq = (const float*)d_in[17];
    const float* Wout = (const float*)d_in[18];
    const float* bout = (const float*)d_in[19];
    const float* lng = (const float*)d_in[20];
    const float* lnb = (const float*)d_in[21];

    int E  = in_sizes[2];
    int nA = in_sizes[0] / NODE_ROW;   // 30000
    int nB = in_sizes[1] / NODE_ROW;   // 30000
    int rowsA = nA * 2;                // N_A * V = 60000
    size_t nodeElems = (size_t)nA * NODE_ROW;   // 7.68M per feature matrix

    // Workspace layout (all bf16 node buffers)
    ushort* fbA  = (ushort*)d_ws;              // feat_A bf16
    ushort* fbB  = fbA + nodeElems;            // feat_B bf16
    ushort* hB   = fbB + nodeElems;            // l2norm(spmm_ab(feat_A)) bf16
    ushort* hA1  = hB + nodeElems;             // spmm_ba(hB) bf16
    ushort* hA2  = hA1 + nodeElems;            // spmm_ba(feat_B) bf16
    ushort* xbuf = hA2 + nodeElems;            // [rowsA, 2, 128] bf16
    ushort* Wbf  = xbuf + (size_t)rowsA * 2 * D;
    ushort* W1b   = Wbf;
    ushort* W2b   = Wbf + 16384;
    ushort* Winb  = Wbf + 32768;
    ushort* Woutb = Wbf + 81920;
    int* cnt_ab   = (int*)(Wbf + 98304);
    int* cnt_ba   = cnt_ab + nB;
    int* start_ab = cnt_ba + nA;
    int* start_ba = start_ab + (nB + 1);
    uintptr_t a = (uintptr_t)(start_ba + (nA + 1));
    a = (a + 15) & ~(uintptr_t)15;
    int2* ep_ab = (int2*)a;
    int2* ep_ba = ep_ab + E;

    int egrid = (E + 255) / 256;
    int n8 = (int)(nodeElems / 8);

    // feature fp32 -> bf16
    k_f2b<<<(n8 + 255) / 256, 256, 0, stream>>>(feat_A, fbA, n8);
    k_f2b<<<(n8 + 255) / 256, 256, 0, stream>>>(feat_B, fbB, n8);

    // CSR build for both graphs
    hipMemsetAsync(cnt_ab, 0, (size_t)(nA + nB) * sizeof(int), stream);
    k_hist<<<egrid, 256, 0, stream>>>(dst_ab, dst_ba, cnt_ab, cnt_ba, E);
    k_scan<<<1, 1024, 0, stream>>>(cnt_ab, start_ab, nB);
    k_scan<<<1, 1024, 0, stream>>>(cnt_ba, start_ba, nA);
    hipMemsetAsync(cnt_ab, 0, (size_t)(nA + nB) * sizeof(int), stream);
    k_scatter<<<egrid, 256, 0, stream>>>(src_ab, dst_ab, val_ab,
                                         src_ba, dst_ba, val_ba,
                                         start_ab, start_ba, cnt_ab, cnt_ba,
                                         ep_ab, ep_ba, E);

    // weights -> bf16
    k_cvt<<<96, 256, 0, stream>>>(W1, W2, Win, Wout, Wbf);

    // metapath aggregations (bf16 reads, fp32 accumulate)
    k_gather_norm_bf<<<(nB + 3) / 4, 256, 0, stream>>>(fbA, ep_ab, start_ab, hB, nB);
    k_gather2_bf<<<(nA + 3) / 4, 256, 0, stream>>>(hB, fbB, ep_ba, start_ba,
                                                   hA1, hA2, nA);

    // dense epilogue: MFMA proj, MFMA attention
    k_projm<<<rowsA / 16, 128, 0, stream>>>(hA1, W1b, b1, g1, be1, xbuf, 0);
    k_projm<<<rowsA / 16, 128, 0, stream>>>(hA2, W2b, b2, g2, be2, xbuf, 1);
    k_attn2<<<rowsA / AP, 384, 0, stream>>>(xbuf, Winb, binq, Woutb, bout,
                                            lng, lnb, (float*)d_out);
}

// Round 6
// 587.755 us; speedup vs baseline: 9.3489x; 1.1030x over previous
//
#include <hip/hip_runtime.h>

// Problem constants: N_A=N_B=30000, V=2, D=128
#define D 128
#define NODE_ROW 256       // V*D elements per node
#define AP 8               // (n,v) pairs per block in k_attn2
#define AR (AP * 2)        // x-rows per block in k_attn2 (P=2)

typedef __attribute__((ext_vector_type(8))) short short8;
typedef __attribute__((ext_vector_type(4))) float floatx4;

__device__ __forceinline__ ushort f2bf(float f) {
    unsigned int u = __float_as_uint(f);
    u += 0x7fffu + ((u >> 16) & 1u);
    return (ushort)(u >> 16);
}
__device__ __forceinline__ unsigned int pk2(float a, float b) {
    return (unsigned int)f2bf(a) | ((unsigned int)f2bf(b) << 16);
}
__device__ __forceinline__ void up8(uint4 u, float* f) {
    f[0] = __uint_as_float(u.x << 16); f[1] = __uint_as_float(u.x & 0xffff0000u);
    f[2] = __uint_as_float(u.y << 16); f[3] = __uint_as_float(u.y & 0xffff0000u);
    f[4] = __uint_as_float(u.z << 16); f[5] = __uint_as_float(u.z & 0xffff0000u);
    f[6] = __uint_as_float(u.w << 16); f[7] = __uint_as_float(u.w & 0xffff0000u);
}
__device__ __forceinline__ float bf2f(ushort h) {
    return __uint_as_float(((unsigned int)h) << 16);
}
__device__ __forceinline__ short8 ldfrag(const ushort* p) {
    union { uint4 u; short8 s; } cv;
    cv.u = *(const uint4*)p;
    return cv.s;
}
__device__ __forceinline__ void acc4(float4& a, float w, uint2 u) {
    a.x += w * __uint_as_float(u.x << 16);
    a.y += w * __uint_as_float(u.x & 0xffff0000u);
    a.z += w * __uint_as_float(u.y << 16);
    a.w += w * __uint_as_float(u.y & 0xffff0000u);
}

// ---------------- fp32 -> bf16 feature convert (both matrices, one launch) ----------------
__global__ __launch_bounds__(256) void k_f2b2(
    const float* __restrict__ srcA, const float* __restrict__ srcB,
    ushort* __restrict__ dstA, ushort* __restrict__ dstB, int n8) {
    int i = blockIdx.x * 256 + threadIdx.x;
    const float* s; ushort* d; int k;
    if (i < n8) { s = srcA; d = dstA; k = i; }
    else if (i < 2 * n8) { s = srcB; d = dstB; k = i - n8; }
    else return;
    const float4* sp = (const float4*)s + (size_t)k * 2;
    float4 a = sp[0], b = sp[1];
    uint4 o;
    o.x = pk2(a.x, a.y); o.y = pk2(a.z, a.w);
    o.z = pk2(b.x, b.y); o.w = pk2(b.z, b.w);
    ((uint4*)d)[k] = o;
}

// ---------------- CSR build (verbatim R2) ----------------

__global__ __launch_bounds__(256) void k_hist(
    const int* __restrict__ dst_ab, const int* __restrict__ dst_ba,
    int* __restrict__ cnt_ab, int* __restrict__ cnt_ba, int E) {
    int i = blockIdx.x * 256 + threadIdx.x;
    if (i >= E) return;
    atomicAdd(&cnt_ab[dst_ab[i]], 1);
    atomicAdd(&cnt_ba[dst_ba[i]], 1);
}

__global__ __launch_bounds__(1024) void k_scan(
    const int* __restrict__ cnt, int* __restrict__ start, int n) {
    __shared__ int part[1024];
    int t = threadIdx.x;
    int chunk = (n + 1023) >> 10;
    int lo = min(t * chunk, n), hi = min(lo + chunk, n);
    int s = 0;
    for (int i = lo; i < hi; i++) s += cnt[i];
    part[t] = s;
    __syncthreads();
    for (int d = 1; d < 1024; d <<= 1) {
        int v = (t >= d) ? part[t - d] : 0;
        __syncthreads();
        part[t] += v;
        __syncthreads();
    }
    int off = part[t] - s;
    for (int i = lo; i < hi; i++) { start[i] = off; off += cnt[i]; }
    if (t == 1023) start[n] = off;
}

__global__ __launch_bounds__(256) void k_scatter(
    const int* __restrict__ src_ab, const int* __restrict__ dst_ab,
    const float* __restrict__ val_ab,
    const int* __restrict__ src_ba, const int* __restrict__ dst_ba,
    const float* __restrict__ val_ba,
    const int* __restrict__ start_ab, const int* __restrict__ start_ba,
    int* __restrict__ cnt_ab, int* __restrict__ cnt_ba,
    int2* __restrict__ ep_ab, int2* __restrict__ ep_ba, int E) {
    int i = blockIdx.x * 256 + threadIdx.x;
    if (i >= E) return;
    {
        int dd = dst_ab[i];
        int pos = start_ab[dd] + atomicAdd(&cnt_ab[dd], 1);
        ep_ab[pos] = make_int2(src_ab[i], __float_as_int(val_ab[i]));
    }
    {
        int dd = dst_ba[i];
        int pos = start_ba[dd] + atomicAdd(&cnt_ba[dd], 1);
        ep_ba[pos] = make_int2(src_ba[i], __float_as_int(val_ba[i]));
    }
}

// ---------------- bf16 gather SpMM (4x unrolled for MLP) ----------------

__global__ __launch_bounds__(256) void k_gather_norm_bf(
    const ushort* __restrict__ feat, const int2* __restrict__ ep,
    const int* __restrict__ start, ushort* __restrict__ out, int n) {
    int node = blockIdx.x * 4 + (threadIdx.x >> 6);
    if (node >= n) return;
    int lane = threadIdx.x & 63;
    int lo = start[node], hi = start[node + 1];
    float4 acc = make_float4(0.f, 0.f, 0.f, 0.f);
    int i = lo;
    for (; i + 3 < hi; i += 4) {
        int2 p0 = ep[i], p1 = ep[i + 1], p2 = ep[i + 2], p3 = ep[i + 3];
        uint2 u0 = ((const uint2*)(feat + (size_t)p0.x * NODE_ROW))[lane];
        uint2 u1 = ((const uint2*)(feat + (size_t)p1.x * NODE_ROW))[lane];
        uint2 u2 = ((const uint2*)(feat + (size_t)p2.x * NODE_ROW))[lane];
        uint2 u3 = ((const uint2*)(feat + (size_t)p3.x * NODE_ROW))[lane];
        acc4(acc, __int_as_float(p0.y), u0);
        acc4(acc, __int_as_float(p1.y), u1);
        acc4(acc, __int_as_float(p2.y), u2);
        acc4(acc, __int_as_float(p3.y), u3);
    }
    for (; i < hi; i++) {
        int2 p = ep[i];
        uint2 u = ((const uint2*)(feat + (size_t)p.x * NODE_ROW))[lane];
        acc4(acc, __int_as_float(p.y), u);
    }
    float ss = acc.x * acc.x + acc.y * acc.y + acc.z * acc.z + acc.w * acc.w;
    #pragma unroll
    for (int o = 16; o > 0; o >>= 1) ss += __shfl_xor(ss, o, 32);
    float sc = 1.0f / fmaxf(sqrtf(ss), 1e-12f);
    uint2 o;
    o.x = pk2(acc.x * sc, acc.y * sc);
    o.y = pk2(acc.z * sc, acc.w * sc);
    ((uint2*)(out + (size_t)node * NODE_ROW))[lane] = o;
}

__global__ __launch_bounds__(256) void k_gather2_bf(
    const ushort* __restrict__ featP, const ushort* __restrict__ featQ,
    const int2* __restrict__ ep, const int* __restrict__ start,
    ushort* __restrict__ outP, ushort* __restrict__ outQ, int n) {
    int node = blockIdx.x * 4 + (threadIdx.x >> 6);
    if (node >= n) return;
    int lane = threadIdx.x & 63;
    int lo = start[node], hi = start[node + 1];
    float4 aP = make_float4(0.f, 0.f, 0.f, 0.f);
    float4 aQ = make_float4(0.f, 0.f, 0.f, 0.f);
    int i = lo;
    for (; i + 3 < hi; i += 4) {
        int2 p0 = ep[i], p1 = ep[i + 1], p2 = ep[i + 2], p3 = ep[i + 3];
        size_t o0 = (size_t)p0.x * NODE_ROW, o1 = (size_t)p1.x * NODE_ROW;
        size_t o2 = (size_t)p2.x * NODE_ROW, o3 = (size_t)p3.x * NODE_ROW;
        uint2 uP0 = ((const uint2*)(featP + o0))[lane];
        uint2 uQ0 = ((const uint2*)(featQ + o0))[lane];
        uint2 uP1 = ((const uint2*)(featP + o1))[lane];
        uint2 uQ1 = ((const uint2*)(featQ + o1))[lane];
        uint2 uP2 = ((const uint2*)(featP + o2))[lane];
        uint2 uQ2 = ((const uint2*)(featQ + o2))[lane];
        uint2 uP3 = ((const uint2*)(featP + o3))[lane];
        uint2 uQ3 = ((const uint2*)(featQ + o3))[lane];
        float w0 = __int_as_float(p0.y), w1 = __int_as_float(p1.y);
        float w2 = __int_as_float(p2.y), w3 = __int_as_float(p3.y);
        acc4(aP, w0, uP0); acc4(aQ, w0, uQ0);
        acc4(aP, w1, uP1); acc4(aQ, w1, uQ1);
        acc4(aP, w2, uP2); acc4(aQ, w2, uQ2);
        acc4(aP, w3, uP3); acc4(aQ, w3, uQ3);
    }
    for (; i < hi; i++) {
        int2 p = ep[i];
        float w = __int_as_float(p.y);
        size_t off = (size_t)p.x * NODE_ROW;
        uint2 uP = ((const uint2*)(featP + off))[lane];
        uint2 uQ = ((const uint2*)(featQ + off))[lane];
        acc4(aP, w, uP); acc4(aQ, w, uQ);
    }
    uint2 oP, oQ;
    oP.x = pk2(aP.x, aP.y); oP.y = pk2(aP.z, aP.w);
    oQ.x = pk2(aQ.x, aQ.y); oQ.y = pk2(aQ.z, aQ.w);
    ((uint2*)(outP + (size_t)node * NODE_ROW))[lane] = oP;
    ((uint2*)(outQ + (size_t)node * NODE_ROW))[lane] = oQ;
}

// ---------------- weight fp32 -> bf16 pre-convert ----------------
__global__ __launch_bounds__(256) void k_cvt(
    const float* __restrict__ W1, const float* __restrict__ W2,
    const float* __restrict__ Win, const float* __restrict__ Wout,
    ushort* __restrict__ dst) {
    int idx = (blockIdx.x * 256 + threadIdx.x) * 4;
    if (idx >= 98304) return;
    const float* s; int off;
    if (idx < 16384)      { s = W1;  off = idx; }
    else if (idx < 32768) { s = W2;  off = idx - 16384; }
    else if (idx < 81920) { s = Win; off = idx - 32768; }
    else                  { s = Wout; off = idx - 81920; }
    float4 f = *(const float4*)(s + off);
    uint2 p;
    p.x = pk2(f.x, f.y);
    p.y = pk2(f.z, f.w);
    *(uint2*)(dst + idx) = p;
}

// ---------------- k_projm (verbatim R5, proven) ----------------
__global__ __launch_bounds__(128) void k_projm(
    const ushort* __restrict__ in, const ushort* __restrict__ Wb,
    const float* __restrict__ b, const float* __restrict__ g,
    const float* __restrict__ be, ushort* __restrict__ xbuf, int p) {
    __shared__ ushort xn[16][136];
    __shared__ float yb[16][128];
    int t = threadIdx.x;
    size_t rowbase = (size_t)blockIdx.x * 16;
    int r = t >> 3, i = t & 7;

    {
        const ushort* gp = in + (rowbase + r) * D + i * 16;
        float v[16];
        up8(((const uint4*)gp)[0], v);
        up8(((const uint4*)gp)[1], v + 8);
        float ss = 0.f;
        #pragma unroll
        for (int e = 0; e < 16; e++) ss += v[e] * v[e];
        ss += __shfl_xor(ss, 1, 8);
        ss += __shfl_xor(ss, 2, 8);
        ss += __shfl_xor(ss, 4, 8);
        float sc = 1.0f / fmaxf(sqrtf(ss), 1e-12f);
        uint4 w0, w1;
        w0.x = pk2(v[0]*sc, v[1]*sc);   w0.y = pk2(v[2]*sc, v[3]*sc);
        w0.z = pk2(v[4]*sc, v[5]*sc);   w0.w = pk2(v[6]*sc, v[7]*sc);
        w1.x = pk2(v[8]*sc, v[9]*sc);   w1.y = pk2(v[10]*sc, v[11]*sc);
        w1.z = pk2(v[12]*sc, v[13]*sc); w1.w = pk2(v[14]*sc, v[15]*sc);
        ushort* dst = &xn[r][i * 16];
        ((uint4*)dst)[0] = w0;
        ((uint4*)dst)[1] = w1;
    }
    __syncthreads();

    {
        int lane = t & 63, w = t >> 6, c = lane & 15, quad = lane >> 4;
        short8 af[4];
        #pragma unroll
        for (int kt = 0; kt < 4; kt++)
            af[kt] = ldfrag(&xn[c][kt * 32 + quad * 8]);
        #pragma unroll
        for (int nt2 = 0; nt2 < 4; nt2++) {
            int j = (w * 4 + nt2) * 16 + c;
            floatx4 acc = {0.f, 0.f, 0.f, 0.f};
            #pragma unroll
            for (int kt = 0; kt < 4; kt++) {
                short8 bfr = ldfrag(Wb + (size_t)j * 128 + kt * 32 + quad * 8);
                acc = __builtin_amdgcn_mfma_f32_16x16x32_bf16(af[kt], bfr, acc, 0, 0, 0);
            }
            float bj = b[j];
            #pragma unroll
            for (int rg = 0; rg < 4; rg++)
                yb[quad * 4 + rg][j] = acc[rg] + bj;
        }
    }
    __syncthreads();

    {
        float v[16];
        const float* yr = &yb[r][i * 16];
        #pragma unroll
        for (int e = 0; e < 16; e++) v[e] = yr[e];
        float s1 = 0.f, s2 = 0.f;
        #pragma unroll
        for (int e = 0; e < 16; e++) { s1 += v[e]; s2 += v[e] * v[e]; }
        s1 += __shfl_xor(s1, 1, 8); s2 += __shfl_xor(s2, 1, 8);
        s1 += __shfl_xor(s1, 2, 8); s2 += __shfl_xor(s2, 2, 8);
        s1 += __shfl_xor(s1, 4, 8); s2 += __shfl_xor(s2, 4, 8);
        float mu = s1 * (1.0f / 128.0f);
        float var = s2 * (1.0f / 128.0f) - mu * mu;
        float rs = rsqrtf(var + 1e-5f);
        const float* gg = g + i * 16;
        const float* bb = be + i * 16;
        float res[16];
        #pragma unroll
        for (int e = 0; e < 16; e++)
            res[e] = fmaxf((v[e] - mu) * rs * gg[e] + bb[e], 0.f);
        ushort* op = xbuf + ((rowbase + r) * 2 + p) * D + i * 16;
        uint4 w0, w1;
        w0.x = pk2(res[0], res[1]);   w0.y = pk2(res[2], res[3]);
        w0.z = pk2(res[4], res[5]);   w0.w = pk2(res[6], res[7]);
        w1.x = pk2(res[8], res[9]);   w1.y = pk2(res[10], res[11]);
        w1.z = pk2(res[12], res[13]); w1.w = pk2(res[14], res[15]);
        ((uint4*)op)[0] = w0;
        ((uint4*)op)[1] = w1;
    }
}

// ---------------- k_attn2: slim-LDS version (29.4KB -> 5 blocks/CU) ----------------
// Changes vs proven R5: xs dropped (residual = bf2f(xb)), os dropped (a@v in
// registers -> ob), v stored bf16 (vb). qk region: q fp32 cols 0..127 (scaled),
// k fp32 cols 128..255; y (out-proj result) overwrites cols 0..127 after scores.
__global__ __launch_bounds__(384, 8) void k_attn2(
    const ushort* __restrict__ xbuf,
    const ushort* __restrict__ Winb, const float* __restrict__ binq,
    const ushort* __restrict__ Woutb, const float* __restrict__ bout,
    const float* __restrict__ lng, const float* __restrict__ lnb,
    float* __restrict__ out) {
    __shared__ ushort xb[AR][136];     // x rows bf16 (A-operand + residual) 4352B
    __shared__ float qk[AR][256];      // q(scaled),k fp32; y reuses 0..127  16384B
    __shared__ ushort vb[AR][136];     // v bf16                              4352B
    __shared__ ushort ob[AR][136];     // attn-out bf16 (A-operand)           4352B
    __shared__ float aw[AP][4][2][2];  //                                      512B
    __shared__ float mu_s[AR], rs_s[AR];
    int t = threadIdx.x;
    int lane = t & 63, w = t >> 6;
    int c = lane & 15, quad = lane >> 4;
    size_t pairbase = (size_t)blockIdx.x * AP;
    size_t rowbase = pairbase * 2;

    // load bf16 x into xb
    const uint2* gx = (const uint2*)(xbuf + rowbase * D);
    for (int i = t; i < AR * D / 4; i += 384) {
        int r = i >> 5;
        int col = (i & 31) * 4;
        *(uint2*)&xb[r][col] = gx[i];
    }
    __syncthreads();

    // QKV GEMM via MFMA: M=16, N=384 (wave w -> ntiles w*4..w*4+3)
    {
        short8 af[4];
        #pragma unroll
        for (int kt = 0; kt < 4; kt++)
            af[kt] = ldfrag(&xb[c][kt * 32 + quad * 8]);
        #pragma unroll
        for (int nt2 = 0; nt2 < 4; nt2++) {
            int j = (w * 4 + nt2) * 16 + c;
            floatx4 acc = {0.f, 0.f, 0.f, 0.f};
            #pragma unroll
            for (int kt = 0; kt < 4; kt++) {
                short8 bfr = ldfrag(Winb + (size_t)j * 128 + kt * 32 + quad * 8);
                acc = __builtin_amdgcn_mfma_f32_16x16x32_bf16(af[kt], bfr, acc, 0, 0, 0);
            }
            float bj = binq[j];
            if (j < 256) {
                float sc = (j < 128) ? 0.17677669529663687f : 1.0f;
                #pragma unroll
                for (int rg = 0; rg < 4; rg++)
                    qk[quad * 4 + rg][j] = (acc[rg] + bj) * sc;
            } else {
                #pragma unroll
                for (int rg = 0; rg < 4; rg++)
                    vb[quad * 4 + rg][j - 256] = f2bf(acc[rg] + bj);
            }
        }
    }
    __syncthreads();

    // scores (2x2 per head) + softmax — fp32 from qk
    if (t < AP * 4) {
        int pp = t >> 2, h = t & 3;
        int r0 = pp * 2, r1 = r0 + 1;
        const float* q0 = &qk[r0][h * 32];
        const float* q1 = &qk[r1][h * 32];
        const float* k0 = &qk[r0][128 + h * 32];
        const float* k1 = &qk[r1][128 + h * 32];
        float s00 = 0, s01 = 0, s10 = 0, s11 = 0;
        #pragma unroll
        for (int e = 0; e < 32; e++) {
            float a0 = q0[e], a1 = q1[e], c0 = k0[e], c1 = k1[e];
            s00 += a0 * c0; s01 += a0 * c1; s10 += a1 * c0; s11 += a1 * c1;
        }
        float m0 = fmaxf(s00, s01);
        float e00 = __expf(s00 - m0), e01 = __expf(s01 - m0);
        float i0 = 1.f / (e00 + e01);
        aw[pp][h][0][0] = e00 * i0; aw[pp][h][0][1] = e01 * i0;
        float m1 = fmaxf(s10, s11);
        float e10 = __expf(s10 - m1), e11 = __expf(s11 - m1);
        float i1 = 1.f / (e10 + e11);
        aw[pp][h][1][0] = e10 * i1; aw[pp][h][1][1] = e11 * i1;
    }
    __syncthreads();

    // o = a @ v (fp32 in regs from bf16 vb) -> pack ob; 512 quads over 384 thr
    for (int q2 = t; q2 < AR * D / 4; q2 += 384) {
        int r = q2 >> 5;
        int col = (q2 & 31) * 4;
        int pp = r >> 1, pq = r & 1, h = col >> 5;
        float a0 = aw[pp][h][pq][0], a1 = aw[pp][h][pq][1];
        uint2 u0 = *(const uint2*)&vb[pp * 2][col];
        uint2 u1 = *(const uint2*)&vb[pp * 2 + 1][col];
        float o0 = a0 * __uint_as_float(u0.x << 16)        + a1 * __uint_as_float(u1.x << 16);
        float o1 = a0 * __uint_as_float(u0.x & 0xffff0000u) + a1 * __uint_as_float(u1.x & 0xffff0000u);
        float o2 = a0 * __uint_as_float(u0.y << 16)        + a1 * __uint_as_float(u1.y << 16);
        float o3 = a0 * __uint_as_float(u0.y & 0xffff0000u) + a1 * __uint_as_float(u1.y & 0xffff0000u);
        uint2 pw;
        pw.x = pk2(o0, o1); pw.y = pk2(o2, o3);
        *(uint2*)&ob[r][col] = pw;
    }
    __syncthreads();

    // out-proj via MFMA + bias + residual -> y in qk cols 0..127 (q,k dead)
    if (w < 4) {
        short8 af[4];
        #pragma unroll
        for (int kt = 0; kt < 4; kt++)
            af[kt] = ldfrag(&ob[c][kt * 32 + quad * 8]);
        #pragma unroll
        for (int nt2 = 0; nt2 < 2; nt2++) {
            int j = (w * 2 + nt2) * 16 + c;
            floatx4 acc = {0.f, 0.f, 0.f, 0.f};
            #pragma unroll
            for (int kt = 0; kt < 4; kt++) {
                short8 bfr = ldfrag(Woutb + (size_t)j * 128 + kt * 32 + quad * 8);
                acc = __builtin_amdgcn_mfma_f32_16x16x32_bf16(af[kt], bfr, acc, 0, 0, 0);
            }
            float bj = bout[j];
            #pragma unroll
            for (int rg = 0; rg < 4; rg++) {
                int row = quad * 4 + rg;
                qk[row][j] = acc[rg] + bj + bf2f(xb[row][j]);
            }
        }
    }
    __syncthreads();

    // LN stats per row on y (qk cols 0..127)
    if (t < 128) {
        int r = t >> 3, i = t & 7;
        float s1 = 0.f, s2 = 0.f;
        const float* yr = &qk[r][i * 16];
        #pragma unroll
        for (int cc = 0; cc < 16; cc++) { float v = yr[cc]; s1 += v; s2 += v * v; }
        s1 += __shfl_down(s1, 4, 8); s2 += __shfl_down(s2, 4, 8);
        s1 += __shfl_down(s1, 2, 8); s2 += __shfl_down(s2, 2, 8);
        s1 += __shfl_down(s1, 1, 8); s2 += __shfl_down(s2, 1, 8);
        if (i == 0) {
            float mu = s1 / D;
            float var = s2 / D - mu * mu;
            mu_s[r] = mu; rs_s[r] = rsqrtf(var + 1e-5f);
        }
    }
    __syncthreads();

    // LN apply + mean over P
    if (t < 128) {
        int j = t;
        float gj = lng[j], bj = lnb[j];
        #pragma unroll
        for (int pp = 0; pp < AP; pp++) {
            int r0 = pp * 2, r1 = r0 + 1;
            float v0 = (qk[r0][j] - mu_s[r0]) * rs_s[r0] * gj + bj;
            float v1 = (qk[r1][j] - mu_s[r1]) * rs_s[r1] * gj + bj;
            out[(pairbase + pp) * D + j] = 0.5f * (v0 + v1);
        }
    }
}

extern "C" void kernel_launch(void* const* d_in, const int* in_sizes, int n_in,
                              void* d_out, int out_size, void* d_ws, size_t ws_size,
                              hipStream_t stream) {
    const float* feat_A = (const float*)d_in[0];
    const float* feat_B = (const float*)d_in[1];
    const int*   src_ab = (const int*)d_in[2];
    const int*   dst_ab = (const int*)d_in[3];
    const float* val_ab = (const float*)d_in[4];
    const int*   src_ba = (const int*)d_in[5];
    const int*   dst_ba = (const int*)d_in[6];
    const float* val_ba = (const float*)d_in[7];
    const float* W1 = (const float*)d_in[8];
    const float* b1 = (const float*)d_in[9];
    const float* g1 = (const float*)d_in[10];
    const float* be1 = (const float*)d_in[11];
    const float* W2 = (const float*)d_in[12];
    const float* b2 = (const float*)d_in[13];
    const float* g2 = (const float*)d_in[14];
    const float* be2 = (const float*)d_in[15];
    const float* Win = (const float*)d_in[16];
    const float* binq = (const float*)d_in[17];
    const float* Wout = (const float*)d_in[18];
    const float* bout = (const float*)d_in[19];
    const float* lng = (const float*)d_in[20];
    const float* lnb = (const float*)d_in[21];

    int E  = in_sizes[2];
    int nA = in_sizes[0] / NODE_ROW;   // 30000
    int nB = in_sizes[1] / NODE_ROW;   // 30000
    int rowsA = nA * 2;                // N_A * V = 60000
    size_t nodeElems = (size_t)nA * NODE_ROW;

    // Workspace layout (identical to passing R5)
    ushort* fbA  = (ushort*)d_ws;
    ushort* fbB  = fbA + nodeElems;
    ushort* hB   = fbB + nodeElems;
    ushort* hA1  = hB + nodeElems;
    ushort* hA2  = hA1 + nodeElems;
    ushort* xbuf = hA2 + nodeElems;
    ushort* Wbf  = xbuf + (size_t)rowsA * 2 * D;
    ushort* W1b   = Wbf;
    ushort* W2b   = Wbf + 16384;
    ushort* Winb  = Wbf + 32768;
    ushort* Woutb = Wbf + 81920;
    int* cnt_ab   = (int*)(Wbf + 98304);
    int* cnt_ba   = cnt_ab + nB;
    int* start_ab = cnt_ba + nA;
    int* start_ba = start_ab + (nB + 1);
    uintptr_t a = (uintptr_t)(start_ba + (nA + 1));
    a = (a + 15) & ~(uintptr_t)15;
    int2* ep_ab = (int2*)a;
    int2* ep_ba = ep_ab + E;

    int egrid = (E + 255) / 256;
    int n8 = (int)(nodeElems / 8);

    // features fp32 -> bf16 (single launch, both matrices)
    k_f2b2<<<(2 * n8 + 255) / 256, 256, 0, stream>>>(feat_A, feat_B, fbA, fbB, n8);

    // CSR build for both graphs
    hipMemsetAsync(cnt_ab, 0, (size_t)(nA + nB) * sizeof(int), stream);
    k_hist<<<egrid, 256, 0, stream>>>(dst_ab, dst_ba, cnt_ab, cnt_ba, E);
    k_scan<<<1, 1024, 0, stream>>>(cnt_ab, start_ab, nB);
    k_scan<<<1, 1024, 0, stream>>>(cnt_ba, start_ba, nA);
    hipMemsetAsync(cnt_ab, 0, (size_t)(nA + nB) * sizeof(int), stream);
    k_scatter<<<egrid, 256, 0, stream>>>(src_ab, dst_ab, val_ab,
                                         src_ba, dst_ba, val_ba,
                                         start_ab, start_ba, cnt_ab, cnt_ba,
                                         ep_ab, ep_ba, E);

    // weights -> bf16
    k_cvt<<<96, 256, 0, stream>>>(W1, W2, Win, Wout, Wbf);

    // metapath aggregations (bf16 reads, fp32 accumulate, 4x unrolled)
    k_gather_norm_bf<<<(nB + 3) / 4, 256, 0, stream>>>(fbA, ep_ab, start_ab, hB, nB);
    k_gather2_bf<<<(nA + 3) / 4, 256, 0, stream>>>(hB, fbB, ep_ba, start_ba,
                                                   hA1, hA2, nA);

    // dense epilogue: MFMA proj, slim MFMA attention
    k_projm<<<rowsA / 16, 128, 0, stream>>>(hA1, W1b, b1, g1, be1, xbuf, 0);
    k_projm<<<rowsA / 16, 128, 0, stream>>>(hA2, W2b, b2, g2, be2, xbuf, 1);
    k_attn2<<<rowsA / AP, 384, 0, stream>>>(xbuf, Winb, binq, Woutb, bout,
                                            lng, lnb, (float*)d_out);
}

// Round 7
// 580.756 us; speedup vs baseline: 9.4615x; 1.0121x over previous
//
#include <hip/hip_runtime.h>

// Problem constants: N_A=N_B=30000, V=2, D=128
#define D 128
#define NODE_ROW 256       // V*D elements per node
#define AP 8               // (n,v) pairs per block in k_attn2
#define AR (AP * 2)        // x-rows per block in k_attn2 (P=2)

typedef __attribute__((ext_vector_type(8))) short short8;
typedef __attribute__((ext_vector_type(4))) float floatx4;

__device__ __forceinline__ ushort f2bf(float f) {
    unsigned int u = __float_as_uint(f);
    u += 0x7fffu + ((u >> 16) & 1u);
    return (ushort)(u >> 16);
}
__device__ __forceinline__ unsigned int pk2(float a, float b) {
    return (unsigned int)f2bf(a) | ((unsigned int)f2bf(b) << 16);
}
__device__ __forceinline__ void up8(uint4 u, float* f) {
    f[0] = __uint_as_float(u.x << 16); f[1] = __uint_as_float(u.x & 0xffff0000u);
    f[2] = __uint_as_float(u.y << 16); f[3] = __uint_as_float(u.y & 0xffff0000u);
    f[4] = __uint_as_float(u.z << 16); f[5] = __uint_as_float(u.z & 0xffff0000u);
    f[6] = __uint_as_float(u.w << 16); f[7] = __uint_as_float(u.w & 0xffff0000u);
}
__device__ __forceinline__ float bf2f(ushort h) {
    return __uint_as_float(((unsigned int)h) << 16);
}
__device__ __forceinline__ short8 ldfrag(const ushort* p) {
    union { uint4 u; short8 s; } cv;
    cv.u = *(const uint4*)p;
    return cv.s;
}
__device__ __forceinline__ void acc4(float4& a, float w, uint2 u) {
    a.x += w * __uint_as_float(u.x << 16);
    a.y += w * __uint_as_float(u.x & 0xffff0000u);
    a.z += w * __uint_as_float(u.y << 16);
    a.w += w * __uint_as_float(u.y & 0xffff0000u);
}

// ---------------- fp32 -> bf16 feature convert (both matrices, one launch) ----------------
__global__ __launch_bounds__(256) void k_f2b2(
    const float* __restrict__ srcA, const float* __restrict__ srcB,
    ushort* __restrict__ dstA, ushort* __restrict__ dstB, int n8) {
    int i = blockIdx.x * 256 + threadIdx.x;
    const float* s; ushort* d; int k;
    if (i < n8) { s = srcA; d = dstA; k = i; }
    else if (i < 2 * n8) { s = srcB; d = dstB; k = i - n8; }
    else return;
    const float4* sp = (const float4*)s + (size_t)k * 2;
    float4 a = sp[0], b = sp[1];
    uint4 o;
    o.x = pk2(a.x, a.y); o.y = pk2(a.z, a.w);
    o.z = pk2(b.x, b.y); o.w = pk2(b.z, b.w);
    ((uint4*)d)[k] = o;
}

// ---------------- CSR build ----------------

__global__ __launch_bounds__(256) void k_hist(
    const int* __restrict__ dst_ab, const int* __restrict__ dst_ba,
    int* __restrict__ cnt_ab, int* __restrict__ cnt_ba, int E) {
    int i = blockIdx.x * 256 + threadIdx.x;
    if (i >= E) return;
    atomicAdd(&cnt_ab[dst_ab[i]], 1);
    atomicAdd(&cnt_ba[dst_ba[i]], 1);
}

// Both scans in one launch (block 0: ab graph, block 1: ba graph).
// Writes exclusive prefix into start[] AND back into cnt[] (scatter cursor).
__global__ __launch_bounds__(1024) void k_scan2(
    int* __restrict__ cntB, int* __restrict__ startB, int nB_,
    int* __restrict__ cntA, int* __restrict__ startA, int nA_) {
    __shared__ int part[1024];
    int* cnt; int* start; int n;
    if (blockIdx.x == 0) { cnt = cntB; start = startB; n = nB_; }
    else                 { cnt = cntA; start = startA; n = nA_; }
    int t = threadIdx.x;
    int chunk = (n + 1023) >> 10;
    int lo = min(t * chunk, n), hi = min(lo + chunk, n);
    int s = 0;
    for (int i = lo; i < hi; i++) s += cnt[i];
    part[t] = s;
    __syncthreads();
    for (int d = 1; d < 1024; d <<= 1) {
        int v = (t >= d) ? part[t - d] : 0;
        __syncthreads();
        part[t] += v;
        __syncthreads();
    }
    int off = part[t] - s;
    for (int i = lo; i < hi; i++) {
        int c = cnt[i];
        start[i] = off;
        cnt[i] = off;          // running cursor for k_scatter
        off += c;
    }
    if (t == 1023) start[n] = off;
}

// scatter with absolute cursors (cnt holds start offsets after k_scan2)
__global__ __launch_bounds__(256) void k_scatter(
    const int* __restrict__ src_ab, const int* __restrict__ dst_ab,
    const float* __restrict__ val_ab,
    const int* __restrict__ src_ba, const int* __restrict__ dst_ba,
    const float* __restrict__ val_ba,
    int* __restrict__ cur_ab, int* __restrict__ cur_ba,
    int2* __restrict__ ep_ab, int2* __restrict__ ep_ba, int E) {
    int i = blockIdx.x * 256 + threadIdx.x;
    if (i >= E) return;
    {
        int pos = atomicAdd(&cur_ab[dst_ab[i]], 1);
        ep_ab[pos] = make_int2(src_ab[i], __float_as_int(val_ab[i]));
    }
    {
        int pos = atomicAdd(&cur_ba[dst_ba[i]], 1);
        ep_ba[pos] = make_int2(src_ba[i], __float_as_int(val_ba[i]));
    }
}

// ---------------- bf16 gather SpMM (4x unrolled for MLP) ----------------

__global__ __launch_bounds__(256) void k_gather_norm_bf(
    const ushort* __restrict__ feat, const int2* __restrict__ ep,
    const int* __restrict__ start, ushort* __restrict__ out, int n) {
    int node = blockIdx.x * 4 + (threadIdx.x >> 6);
    if (node >= n) return;
    int lane = threadIdx.x & 63;
    int lo = start[node], hi = start[node + 1];
    float4 acc = make_float4(0.f, 0.f, 0.f, 0.f);
    int i = lo;
    for (; i + 3 < hi; i += 4) {
        int2 p0 = ep[i], p1 = ep[i + 1], p2 = ep[i + 2], p3 = ep[i + 3];
        uint2 u0 = ((const uint2*)(feat + (size_t)p0.x * NODE_ROW))[lane];
        uint2 u1 = ((const uint2*)(feat + (size_t)p1.x * NODE_ROW))[lane];
        uint2 u2 = ((const uint2*)(feat + (size_t)p2.x * NODE_ROW))[lane];
        uint2 u3 = ((const uint2*)(feat + (size_t)p3.x * NODE_ROW))[lane];
        acc4(acc, __int_as_float(p0.y), u0);
        acc4(acc, __int_as_float(p1.y), u1);
        acc4(acc, __int_as_float(p2.y), u2);
        acc4(acc, __int_as_float(p3.y), u3);
    }
    for (; i < hi; i++) {
        int2 p = ep[i];
        uint2 u = ((const uint2*)(feat + (size_t)p.x * NODE_ROW))[lane];
        acc4(acc, __int_as_float(p.y), u);
    }
    float ss = acc.x * acc.x + acc.y * acc.y + acc.z * acc.z + acc.w * acc.w;
    #pragma unroll
    for (int o = 16; o > 0; o >>= 1) ss += __shfl_xor(ss, o, 32);
    float sc = 1.0f / fmaxf(sqrtf(ss), 1e-12f);
    uint2 o;
    o.x = pk2(acc.x * sc, acc.y * sc);
    o.y = pk2(acc.z * sc, acc.w * sc);
    ((uint2*)(out + (size_t)node * NODE_ROW))[lane] = o;
}

__global__ __launch_bounds__(256) void k_gather2_bf(
    const ushort* __restrict__ featP, const ushort* __restrict__ featQ,
    const int2* __restrict__ ep, const int* __restrict__ start,
    ushort* __restrict__ outP, ushort* __restrict__ outQ, int n) {
    int node = blockIdx.x * 4 + (threadIdx.x >> 6);
    if (node >= n) return;
    int lane = threadIdx.x & 63;
    int lo = start[node], hi = start[node + 1];
    float4 aP = make_float4(0.f, 0.f, 0.f, 0.f);
    float4 aQ = make_float4(0.f, 0.f, 0.f, 0.f);
    int i = lo;
    for (; i + 3 < hi; i += 4) {
        int2 p0 = ep[i], p1 = ep[i + 1], p2 = ep[i + 2], p3 = ep[i + 3];
        size_t o0 = (size_t)p0.x * NODE_ROW, o1 = (size_t)p1.x * NODE_ROW;
        size_t o2 = (size_t)p2.x * NODE_ROW, o3 = (size_t)p3.x * NODE_ROW;
        uint2 uP0 = ((const uint2*)(featP + o0))[lane];
        uint2 uQ0 = ((const uint2*)(featQ + o0))[lane];
        uint2 uP1 = ((const uint2*)(featP + o1))[lane];
        uint2 uQ1 = ((const uint2*)(featQ + o1))[lane];
        uint2 uP2 = ((const uint2*)(featP + o2))[lane];
        uint2 uQ2 = ((const uint2*)(featQ + o2))[lane];
        uint2 uP3 = ((const uint2*)(featP + o3))[lane];
        uint2 uQ3 = ((const uint2*)(featQ + o3))[lane];
        float w0 = __int_as_float(p0.y), w1 = __int_as_float(p1.y);
        float w2 = __int_as_float(p2.y), w3 = __int_as_float(p3.y);
        acc4(aP, w0, uP0); acc4(aQ, w0, uQ0);
        acc4(aP, w1, uP1); acc4(aQ, w1, uQ1);
        acc4(aP, w2, uP2); acc4(aQ, w2, uQ2);
        acc4(aP, w3, uP3); acc4(aQ, w3, uQ3);
    }
    for (; i < hi; i++) {
        int2 p = ep[i];
        float w = __int_as_float(p.y);
        size_t off = (size_t)p.x * NODE_ROW;
        uint2 uP = ((const uint2*)(featP + off))[lane];
        uint2 uQ = ((const uint2*)(featQ + off))[lane];
        acc4(aP, w, uP); acc4(aQ, w, uQ);
    }
    uint2 oP, oQ;
    oP.x = pk2(aP.x, aP.y); oP.y = pk2(aP.z, aP.w);
    oQ.x = pk2(aQ.x, aQ.y); oQ.y = pk2(aQ.z, aQ.w);
    ((uint2*)(outP + (size_t)node * NODE_ROW))[lane] = oP;
    ((uint2*)(outQ + (size_t)node * NODE_ROW))[lane] = oQ;
}

// ---------------- weight fp32 -> bf16 pre-convert ----------------
__global__ __launch_bounds__(256) void k_cvt(
    const float* __restrict__ W1, const float* __restrict__ W2,
    const float* __restrict__ Win, const float* __restrict__ Wout,
    ushort* __restrict__ dst) {
    int idx = (blockIdx.x * 256 + threadIdx.x) * 4;
    if (idx >= 98304) return;
    const float* s; int off;
    if (idx < 16384)      { s = W1;  off = idx; }
    else if (idx < 32768) { s = W2;  off = idx - 16384; }
    else if (idx < 81920) { s = Win; off = idx - 32768; }
    else                  { s = Wout; off = idx - 81920; }
    float4 f = *(const float4*)(s + off);
    uint2 p;
    p.x = pk2(f.x, f.y);
    p.y = pk2(f.z, f.w);
    *(uint2*)(dst + idx) = p;
}

// ---------------- k_projm (verbatim R5, proven) ----------------
__global__ __launch_bounds__(128) void k_projm(
    const ushort* __restrict__ in, const ushort* __restrict__ Wb,
    const float* __restrict__ b, const float* __restrict__ g,
    const float* __restrict__ be, ushort* __restrict__ xbuf, int p) {
    __shared__ ushort xn[16][136];
    __shared__ float yb[16][128];
    int t = threadIdx.x;
    size_t rowbase = (size_t)blockIdx.x * 16;
    int r = t >> 3, i = t & 7;

    {
        const ushort* gp = in + (rowbase + r) * D + i * 16;
        float v[16];
        up8(((const uint4*)gp)[0], v);
        up8(((const uint4*)gp)[1], v + 8);
        float ss = 0.f;
        #pragma unroll
        for (int e = 0; e < 16; e++) ss += v[e] * v[e];
        ss += __shfl_xor(ss, 1, 8);
        ss += __shfl_xor(ss, 2, 8);
        ss += __shfl_xor(ss, 4, 8);
        float sc = 1.0f / fmaxf(sqrtf(ss), 1e-12f);
        uint4 w0, w1;
        w0.x = pk2(v[0]*sc, v[1]*sc);   w0.y = pk2(v[2]*sc, v[3]*sc);
        w0.z = pk2(v[4]*sc, v[5]*sc);   w0.w = pk2(v[6]*sc, v[7]*sc);
        w1.x = pk2(v[8]*sc, v[9]*sc);   w1.y = pk2(v[10]*sc, v[11]*sc);
        w1.z = pk2(v[12]*sc, v[13]*sc); w1.w = pk2(v[14]*sc, v[15]*sc);
        ushort* dst = &xn[r][i * 16];
        ((uint4*)dst)[0] = w0;
        ((uint4*)dst)[1] = w1;
    }
    __syncthreads();

    {
        int lane = t & 63, w = t >> 6, c = lane & 15, quad = lane >> 4;
        short8 af[4];
        #pragma unroll
        for (int kt = 0; kt < 4; kt++)
            af[kt] = ldfrag(&xn[c][kt * 32 + quad * 8]);
        #pragma unroll
        for (int nt2 = 0; nt2 < 4; nt2++) {
            int j = (w * 4 + nt2) * 16 + c;
            floatx4 acc = {0.f, 0.f, 0.f, 0.f};
            #pragma unroll
            for (int kt = 0; kt < 4; kt++) {
                short8 bfr = ldfrag(Wb + (size_t)j * 128 + kt * 32 + quad * 8);
                acc = __builtin_amdgcn_mfma_f32_16x16x32_bf16(af[kt], bfr, acc, 0, 0, 0);
            }
            float bj = b[j];
            #pragma unroll
            for (int rg = 0; rg < 4; rg++)
                yb[quad * 4 + rg][j] = acc[rg] + bj;
        }
    }
    __syncthreads();

    {
        float v[16];
        const float* yr = &yb[r][i * 16];
        #pragma unroll
        for (int e = 0; e < 16; e++) v[e] = yr[e];
        float s1 = 0.f, s2 = 0.f;
        #pragma unroll
        for (int e = 0; e < 16; e++) { s1 += v[e]; s2 += v[e] * v[e]; }
        s1 += __shfl_xor(s1, 1, 8); s2 += __shfl_xor(s2, 1, 8);
        s1 += __shfl_xor(s1, 2, 8); s2 += __shfl_xor(s2, 2, 8);
        s1 += __shfl_xor(s1, 4, 8); s2 += __shfl_xor(s2, 4, 8);
        float mu = s1 * (1.0f / 128.0f);
        float var = s2 * (1.0f / 128.0f) - mu * mu;
        float rs = rsqrtf(var + 1e-5f);
        const float* gg = g + i * 16;
        const float* bb = be + i * 16;
        float res[16];
        #pragma unroll
        for (int e = 0; e < 16; e++)
            res[e] = fmaxf((v[e] - mu) * rs * gg[e] + bb[e], 0.f);
        ushort* op = xbuf + ((rowbase + r) * 2 + p) * D + i * 16;
        uint4 w0, w1;
        w0.x = pk2(res[0], res[1]);   w0.y = pk2(res[2], res[3]);
        w0.z = pk2(res[4], res[5]);   w0.w = pk2(res[6], res[7]);
        w1.x = pk2(res[8], res[9]);   w1.y = pk2(res[10], res[11]);
        w1.z = pk2(res[12], res[13]); w1.w = pk2(res[14], res[15]);
        ((uint4*)op)[0] = w0;
        ((uint4*)op)[1] = w1;
    }
}

// ---------------- k_attn2: slim LDS + fused scores/softmax/a@v phase ----------------
__global__ __launch_bounds__(384, 8) void k_attn2(
    const ushort* __restrict__ xbuf,
    const ushort* __restrict__ Winb, const float* __restrict__ binq,
    const ushort* __restrict__ Woutb, const float* __restrict__ bout,
    const float* __restrict__ lng, const float* __restrict__ lnb,
    float* __restrict__ out) {
    __shared__ ushort xb[AR][136];     // x rows bf16 (A-operand + residual)
    __shared__ float qk[AR][256];      // q(scaled),k fp32; y reuses 0..127
    __shared__ ushort vb[AR][136];     // v bf16
    __shared__ ushort ob[AR][136];     // attn-out bf16 (A-operand)
    __shared__ float mu_s[AR], rs_s[AR];
    int t = threadIdx.x;
    int lane = t & 63, w = t >> 6;
    int c = lane & 15, quad = lane >> 4;
    size_t pairbase = (size_t)blockIdx.x * AP;
    size_t rowbase = pairbase * 2;

    // load bf16 x into xb
    const uint2* gx = (const uint2*)(xbuf + rowbase * D);
    for (int i = t; i < AR * D / 4; i += 384) {
        int r = i >> 5;
        int col = (i & 31) * 4;
        *(uint2*)&xb[r][col] = gx[i];
    }
    __syncthreads();

    // QKV GEMM via MFMA: M=16, N=384 (wave w -> ntiles w*4..w*4+3)
    {
        short8 af[4];
        #pragma unroll
        for (int kt = 0; kt < 4; kt++)
            af[kt] = ldfrag(&xb[c][kt * 32 + quad * 8]);
        #pragma unroll
        for (int nt2 = 0; nt2 < 4; nt2++) {
            int j = (w * 4 + nt2) * 16 + c;
            floatx4 acc = {0.f, 0.f, 0.f, 0.f};
            #pragma unroll
            for (int kt = 0; kt < 4; kt++) {
                short8 bfr = ldfrag(Winb + (size_t)j * 128 + kt * 32 + quad * 8);
                acc = __builtin_amdgcn_mfma_f32_16x16x32_bf16(af[kt], bfr, acc, 0, 0, 0);
            }
            float bj = binq[j];
            if (j < 256) {
                float sc = (j < 128) ? 0.17677669529663687f : 1.0f;
                #pragma unroll
                for (int rg = 0; rg < 4; rg++)
                    qk[quad * 4 + rg][j] = (acc[rg] + bj) * sc;
            } else {
                #pragma unroll
                for (int rg = 0; rg < 4; rg++)
                    vb[quad * 4 + rg][j - 256] = f2bf(acc[rg] + bj);
            }
        }
    }
    __syncthreads();

    // FUSED scores + softmax + a@v: 256 threads, attention weights in registers.
    // t = [pp:3][h:2][pq:1][kk:1][half:1]; each thread: 16-elem partial dot,
    // shfl(1) completes dot, shfl(2) exchanges the two scores, then writes its
    // 8 output columns of ob.
    if (t < 256) {
        int half = t & 1, kk = (t >> 1) & 1, pq = (t >> 2) & 1;
        int h = (t >> 3) & 3, pp = t >> 5;
        int qrow = 2 * pp + pq;
        const float4* qp = (const float4*)&qk[qrow][h * 32 + half * 16];
        const float4* kp = (const float4*)&qk[2 * pp + kk][128 + h * 32 + half * 16];
        float s = 0.f;
        #pragma unroll
        for (int m = 0; m < 4; m++) {
            float4 qv = qp[m], kv = kp[m];
            s += qv.x * kv.x + qv.y * kv.y + qv.z * kv.z + qv.w * kv.w;
        }
        s += __shfl_xor(s, 1, 64);          // complete 32-elem dot
        float so = __shfl_xor(s, 2, 64);    // partner score (other kk)
        float s0 = kk ? so : s;
        float s1 = kk ? s : so;
        float m0 = fmaxf(s0, s1);
        float e0 = __expf(s0 - m0), e1 = __expf(s1 - m0);
        float inv = 1.f / (e0 + e1);
        float a0 = e0 * inv, a1 = e1 * inv;
        int cbase = h * 32 + kk * 16 + half * 8;
        const uint2* v0p = (const uint2*)&vb[2 * pp][cbase];
        const uint2* v1p = (const uint2*)&vb[2 * pp + 1][cbase];
        ushort* op = &ob[qrow][cbase];
        #pragma unroll
        for (int m = 0; m < 2; m++) {
            uint2 u0 = v0p[m], u1 = v1p[m];
            float o0 = a0 * __uint_as_float(u0.x << 16)         + a1 * __uint_as_float(u1.x << 16);
            float o1 = a0 * __uint_as_float(u0.x & 0xffff0000u) + a1 * __uint_as_float(u1.x & 0xffff0000u);
            float o2 = a0 * __uint_as_float(u0.y << 16)         + a1 * __uint_as_float(u1.y << 16);
            float o3 = a0 * __uint_as_float(u0.y & 0xffff0000u) + a1 * __uint_as_float(u1.y & 0xffff0000u);
            uint2 pw;
            pw.x = pk2(o0, o1); pw.y = pk2(o2, o3);
            ((uint2*)op)[m] = pw;
        }
    }
    __syncthreads();

    // out-proj via MFMA + bias + residual -> y in qk cols 0..127 (q,k dead)
    if (w < 4) {
        short8 af[4];
        #pragma unroll
        for (int kt = 0; kt < 4; kt++)
            af[kt] = ldfrag(&ob[c][kt * 32 + quad * 8]);
        #pragma unroll
        for (int nt2 = 0; nt2 < 2; nt2++) {
            int j = (w * 2 + nt2) * 16 + c;
            floatx4 acc = {0.f, 0.f, 0.f, 0.f};
            #pragma unroll
            for (int kt = 0; kt < 4; kt++) {
                short8 bfr = ldfrag(Woutb + (size_t)j * 128 + kt * 32 + quad * 8);
                acc = __builtin_amdgcn_mfma_f32_16x16x32_bf16(af[kt], bfr, acc, 0, 0, 0);
            }
            float bj = bout[j];
            #pragma unroll
            for (int rg = 0; rg < 4; rg++) {
                int row = quad * 4 + rg;
                qk[row][j] = acc[rg] + bj + bf2f(xb[row][j]);
            }
        }
    }
    __syncthreads();

    // LN stats per row on y (qk cols 0..127)
    if (t < 128) {
        int r = t >> 3, i = t & 7;
        float s1 = 0.f, s2 = 0.f;
        const float* yr = &qk[r][i * 16];
        #pragma unroll
        for (int cc = 0; cc < 16; cc++) { float v = yr[cc]; s1 += v; s2 += v * v; }
        s1 += __shfl_down(s1, 4, 8); s2 += __shfl_down(s2, 4, 8);
        s1 += __shfl_down(s1, 2, 8); s2 += __shfl_down(s2, 2, 8);
        s1 += __shfl_down(s1, 1, 8); s2 += __shfl_down(s2, 1, 8);
        if (i == 0) {
            float mu = s1 / D;
            float var = s2 / D - mu * mu;
            mu_s[r] = mu; rs_s[r] = rsqrtf(var + 1e-5f);
        }
    }
    __syncthreads();

    // LN apply + mean over P
    if (t < 128) {
        int j = t;
        float gj = lng[j], bj = lnb[j];
        #pragma unroll
        for (int pp = 0; pp < AP; pp++) {
            int r0 = pp * 2, r1 = r0 + 1;
            float v0 = (qk[r0][j] - mu_s[r0]) * rs_s[r0] * gj + bj;
            float v1 = (qk[r1][j] - mu_s[r1]) * rs_s[r1] * gj + bj;
            out[(pairbase + pp) * D + j] = 0.5f * (v0 + v1);
        }
    }
}

extern "C" void kernel_launch(void* const* d_in, const int* in_sizes, int n_in,
                              void* d_out, int out_size, void* d_ws, size_t ws_size,
                              hipStream_t stream) {
    const float* feat_A = (const float*)d_in[0];
    const float* feat_B = (const float*)d_in[1];
    const int*   src_ab = (const int*)d_in[2];
    const int*   dst_ab = (const int*)d_in[3];
    const float* val_ab = (const float*)d_in[4];
    const int*   src_ba = (const int*)d_in[5];
    const int*   dst_ba = (const int*)d_in[6];
    const float* val_ba = (const float*)d_in[7];
    const float* W1 = (const float*)d_in[8];
    const float* b1 = (const float*)d_in[9];
    const float* g1 = (const float*)d_in[10];
    const float* be1 = (const float*)d_in[11];
    const float* W2 = (const float*)d_in[12];
    const float* b2 = (const float*)d_in[13];
    const float* g2 = (const float*)d_in[14];
    const float* be2 = (const float*)d_in[15];
    const float* Win = (const float*)d_in[16];
    const float* binq = (const float*)d_in[17];
    const float* Wout = (const float*)d_in[18];
    const float* bout = (const float*)d_in[19];
    const float* lng = (const float*)d_in[20];
    const float* lnb = (const float*)d_in[21];

    int E  = in_sizes[2];
    int nA = in_sizes[0] / NODE_ROW;   // 30000
    int nB = in_sizes[1] / NODE_ROW;   // 30000
    int rowsA = nA * 2;                // N_A * V = 60000
    size_t nodeElems = (size_t)nA * NODE_ROW;

    // Workspace layout (identical to passing R6)
    ushort* fbA  = (ushort*)d_ws;
    ushort* fbB  = fbA + nodeElems;
    ushort* hB   = fbB + nodeElems;
    ushort* hA1  = hB + nodeElems;
    ushort* hA2  = hA1 + nodeElems;
    ushort* xbuf = hA2 + nodeElems;
    ushort* Wbf  = xbuf + (size_t)rowsA * 2 * D;
    ushort* W1b   = Wbf;
    ushort* W2b   = Wbf + 16384;
    ushort* Winb  = Wbf + 32768;
    ushort* Woutb = Wbf + 81920;
    int* cnt_ab   = (int*)(Wbf + 98304);
    int* cnt_ba   = cnt_ab + nB;
    int* start_ab = cnt_ba + nA;
    int* start_ba = start_ab + (nB + 1);
    uintptr_t a = (uintptr_t)(start_ba + (nA + 1));
    a = (a + 15) & ~(uintptr_t)15;
    int2* ep_ab = (int2*)a;
    int2* ep_ba = ep_ab + E;

    int egrid = (E + 255) / 256;
    int n8 = (int)(nodeElems / 8);

    // features fp32 -> bf16 (single launch, both matrices)
    k_f2b2<<<(2 * n8 + 255) / 256, 256, 0, stream>>>(feat_A, feat_B, fbA, fbB, n8);

    // CSR build for both graphs (dual scan; cnt becomes the scatter cursor)
    hipMemsetAsync(cnt_ab, 0, (size_t)(nA + nB) * sizeof(int), stream);
    k_hist<<<egrid, 256, 0, stream>>>(dst_ab, dst_ba, cnt_ab, cnt_ba, E);
    k_scan2<<<2, 1024, 0, stream>>>(cnt_ab, start_ab, nB, cnt_ba, start_ba, nA);
    k_scatter<<<egrid, 256, 0, stream>>>(src_ab, dst_ab, val_ab,
                                         src_ba, dst_ba, val_ba,
                                         cnt_ab, cnt_ba, ep_ab, ep_ba, E);

    // weights -> bf16
    k_cvt<<<96, 256, 0, stream>>>(W1, W2, Win, Wout, Wbf);

    // metapath aggregations (bf16 reads, fp32 accumulate, 4x unrolled)
    k_gather_norm_bf<<<(nB + 3) / 4, 256, 0, stream>>>(fbA, ep_ab, start_ab, hB, nB);
    k_gather2_bf<<<(nA + 3) / 4, 256, 0, stream>>>(hB, fbB, ep_ba, start_ba,
                                                   hA1, hA2, nA);

    // dense epilogue: MFMA proj, slim MFMA attention
    k_projm<<<rowsA / 16, 128, 0, stream>>>(hA1, W1b, b1, g1, be1, xbuf, 0);
    k_projm<<<rowsA / 16, 128, 0, stream>>>(hA2, W2b, b2, g2, be2, xbuf, 1);
    k_attn2<<<rowsA / AP, 384, 0, stream>>>(xbuf, Winb, binq, Woutb, bout,
                                            lng, lnb, (float*)d_out);
}